// Round 1
// baseline (1297.498 us; speedup 1.0000x reference)
//
#include <hip/hip_runtime.h>
#include <hip/hip_bf16.h>
#include <math.h>

#define D 2048
#define M_ROWS 50000
#define B_ROWS 16384
#define TOPK 5
#define EPSN 1e-12f

typedef __attribute__((ext_vector_type(4))) float f32x4;
typedef __attribute__((ext_vector_type(8))) short s16x8;
typedef __attribute__((ext_vector_type(4))) unsigned short u16x4;

__device__ __forceinline__ unsigned short f2bf(float f) {
  union { float f; unsigned int u; } x; x.f = f;
  unsigned int u = x.u;
  unsigned int r = u + 0x7fffu + ((u >> 16) & 1u);
  return (unsigned short)(r >> 16);
}

// ---------------- K0: q_norm ----------------
__global__ void k_qnorm(const float* __restrict__ ce, float* __restrict__ qn) {
  __shared__ float red[256];
  int tid = threadIdx.x;
  float s = 0.f;
  for (int t = tid; t < D; t += 256) { float x = ce[t]; s += x * x; }
  red[tid] = s; __syncthreads();
  for (int w = 128; w > 0; w >>= 1) { if (tid < w) red[tid] += red[tid + w]; __syncthreads(); }
  float inv = 1.0f / fmaxf(sqrtf(red[0]), EPSN);
  for (int t = tid; t < D; t += 256) qn[t] = ce[t] * inv;
}

// ---------------- K1: sims over memory bank ----------------
__global__ void k_sims(const float* __restrict__ bank, const float* __restrict__ qn,
                       float* __restrict__ sims) {
  __shared__ float qs[D];
  int tid = threadIdx.x;
  for (int t = tid; t < D; t += 256) qs[t] = qn[t];
  __syncthreads();
  int lane = tid & 63, wid = tid >> 6;
  int gw = (blockIdx.x << 2) + wid;
  int nw = gridDim.x << 2;
  for (int m = gw; m < M_ROWS; m += nw) {
    const float* row = bank + (size_t)m * D;
    float dot = 0.f, sq = 0.f;
#pragma unroll
    for (int i = 0; i < 8; ++i) {
      int off = i * 256 + lane * 4;
      f32x4 a = *(const f32x4*)(row + off);
      f32x4 q = *(const f32x4*)(qs + off);
      dot += a[0]*q[0] + a[1]*q[1] + a[2]*q[2] + a[3]*q[3];
      sq  += a[0]*a[0] + a[1]*a[1] + a[2]*a[2] + a[3]*a[3];
    }
    for (int off = 32; off; off >>= 1) {
      dot += __shfl_xor(dot, off, 64);
      sq  += __shfl_xor(sq,  off, 64);
    }
    if (lane == 0) sims[m] = dot / fmaxf(sqrtf(sq), EPSN);
  }
}

// ---------------- K2: top-5 ----------------
__global__ void k_topk(const float* __restrict__ sims, float* __restrict__ top_sims,
                       int* __restrict__ top_idx) {
  __shared__ float sval[256 * TOPK];
  __shared__ int   sidx[256 * TOPK];
  int tid = threadIdx.x;
  float lv[TOPK]; int li[TOPK];
#pragma unroll
  for (int j = 0; j < TOPK; ++j) { lv[j] = -INFINITY; li[j] = 0x7fffffff; }
  for (int m = tid; m < M_ROWS; m += 256) {
    float v = sims[m];
    if (v > lv[TOPK-1] || (v == lv[TOPK-1] && m < li[TOPK-1])) {
      lv[TOPK-1] = v; li[TOPK-1] = m;
#pragma unroll
      for (int j = TOPK-1; j > 0; --j) {
        bool sw = (lv[j] > lv[j-1]) || (lv[j] == lv[j-1] && li[j] < li[j-1]);
        if (sw) { float tv=lv[j]; lv[j]=lv[j-1]; lv[j-1]=tv; int ti=li[j]; li[j]=li[j-1]; li[j-1]=ti; }
      }
    }
  }
#pragma unroll
  for (int j = 0; j < TOPK; ++j) { sval[tid*TOPK+j] = lv[j]; sidx[tid*TOPK+j] = li[j]; }
  __syncthreads();
  if (tid == 0) {
    float bvv[TOPK]; int bii[TOPK];
    for (int j = 0; j < TOPK; ++j) { bvv[j] = -INFINITY; bii[j] = 0x7fffffff; }
    for (int c = 0; c < 256 * TOPK; ++c) {
      float v = sval[c]; int i = sidx[c];
      if (v > bvv[TOPK-1] || (v == bvv[TOPK-1] && i < bii[TOPK-1])) {
        bvv[TOPK-1] = v; bii[TOPK-1] = i;
        for (int j = TOPK-1; j > 0; --j) {
          bool sw = (bvv[j] > bvv[j-1]) || (bvv[j] == bvv[j-1] && bii[j] < bii[j-1]);
          if (sw) { float tv=bvv[j]; bvv[j]=bvv[j-1]; bvv[j-1]=tv; int ti=bii[j]; bii[j]=bii[j-1]; bii[j-1]=ti; }
        }
      }
    }
    for (int j = 0; j < TOPK; ++j) { top_sims[j] = bvv[j]; top_idx[j] = bii[j]; }
  }
}

// ---------------- K3: k,v = memories @ Wk/Wv^T + b ----------------
__global__ void k_kv(const float* __restrict__ mvals, const int* __restrict__ top_idx,
                     const float* __restrict__ Wk, const float* __restrict__ bk,
                     const float* __restrict__ Wv, const float* __restrict__ bvp,
                     float* __restrict__ kb, float* __restrict__ vb) {
  __shared__ float mem[TOPK][D];
  int tid = threadIdx.x;
  for (int j = 0; j < TOPK; ++j) {
    const float* src = mvals + (size_t)top_idx[j] * D;
    for (int t = tid; t < D; t += 256) mem[j][t] = src[t];
  }
  __syncthreads();
  int lane = tid & 63, wid = tid >> 6;
  int c = blockIdx.x * 4 + wid;
  const float* wkr = Wk + (size_t)c * D;
  const float* wvr = Wv + (size_t)c * D;
  float ak[TOPK] = {0,0,0,0,0}, av[TOPK] = {0,0,0,0,0};
#pragma unroll 2
  for (int i = 0; i < 8; ++i) {
    int off = i * 256 + lane * 4;
    f32x4 wk4 = *(const f32x4*)(wkr + off);
    f32x4 wv4 = *(const f32x4*)(wvr + off);
#pragma unroll
    for (int j = 0; j < TOPK; ++j) {
      f32x4 mv = *(const f32x4*)(&mem[j][off]);
      ak[j] += mv[0]*wk4[0] + mv[1]*wk4[1] + mv[2]*wk4[2] + mv[3]*wk4[3];
      av[j] += mv[0]*wv4[0] + mv[1]*wv4[1] + mv[2]*wv4[2] + mv[3]*wv4[3];
    }
  }
  for (int off = 32; off; off >>= 1) {
#pragma unroll
    for (int j = 0; j < TOPK; ++j) {
      ak[j] += __shfl_xor(ak[j], off, 64);
      av[j] += __shfl_xor(av[j], off, 64);
    }
  }
  if (lane == 0) {
#pragma unroll
    for (int j = 0; j < TOPK; ++j) { kb[j*D + c] = ak[j] + bk[c]; vb[j*D + c] = av[j] + bvp[c]; }
  }
}

// ---------------- K4: KQ = k@Wq, VW = v@WgB^T, sbias = bq·k ----------------
__global__ void k_misc(const float* __restrict__ Wq, const float* __restrict__ bq,
                       const float* __restrict__ Wg,
                       const float* __restrict__ kb, const float* __restrict__ vb,
                       float* __restrict__ KQ, float* __restrict__ VW,
                       float* __restrict__ sbias) {
  __shared__ float sh[TOPK * D];
  int tid = threadIdx.x;
  int bid = blockIdx.x;
  if (bid < 8) {
    // KQ[j,t] = sum_c k[j,c] * Wq[c,t]
    for (int x = tid; x < TOPK * D; x += 256) sh[x] = kb[x];
    __syncthreads();
    int t = bid * 256 + tid;
    float acc[TOPK] = {0,0,0,0,0};
#pragma unroll 8
    for (int c = 0; c < D; ++c) {
      float w = Wq[(size_t)c * D + t];
#pragma unroll
      for (int j = 0; j < TOPK; ++j) acc[j] += sh[j*D + c] * w;
    }
    for (int j = 0; j < TOPK; ++j) KQ[j*D + t] = acc[j];
  } else if (bid < 8 + 512) {
    // VW[j,c] = sum_t v[j,t] * Wg[c, D+t]
    for (int x = tid; x < TOPK * D; x += 256) sh[x] = vb[x];
    __syncthreads();
    int lane = tid & 63, wid = tid >> 6;
    int c = (bid - 8) * 4 + wid;
    const float* wg = Wg + (size_t)c * (2 * D) + D;
    float acc[TOPK] = {0,0,0,0,0};
#pragma unroll 2
    for (int i = 0; i < 8; ++i) {
      int off = i * 256 + lane * 4;
      f32x4 g4 = *(const f32x4*)(wg + off);
#pragma unroll
      for (int j = 0; j < TOPK; ++j) {
        f32x4 vv = *(const f32x4*)(&sh[j*D + off]);
        acc[j] += vv[0]*g4[0] + vv[1]*g4[1] + vv[2]*g4[2] + vv[3]*g4[3];
      }
    }
    for (int off = 32; off; off >>= 1)
#pragma unroll
      for (int j = 0; j < TOPK; ++j) acc[j] += __shfl_xor(acc[j], off, 64);
    if (lane == 0)
      for (int j = 0; j < TOPK; ++j) VW[j*D + c] = acc[j];
  } else {
    // sbias[j] = dot(bq, k[j])
    for (int j = 0; j < TOPK; ++j) {
      float s = 0.f;
      for (int t = tid; t < D; t += 256) s += bq[t] * kb[j*D + t];
      sh[tid] = s; __syncthreads();
      for (int w = 128; w > 0; w >>= 1) { if (tid < w) sh[tid] += sh[tid + w]; __syncthreads(); }
      if (tid == 0) sbias[j] = sh[0];
      __syncthreads();
    }
  }
}

// ---------------- K5: scores + softmax -> attn[B][5] ----------------
__global__ void k_attn(const float* __restrict__ no, const float* __restrict__ KQ,
                       const float* __restrict__ sbias, const float* __restrict__ top_sims,
                       float* __restrict__ attn) {
  __shared__ float kq[TOPK * D];
  int tid = threadIdx.x;
  for (int x = tid; x < TOPK * D; x += 256) kq[x] = KQ[x];
  __syncthreads();
  int lane = tid & 63, wid = tid >> 6;
  int gw = blockIdx.x * 4 + wid, nw = gridDim.x * 4;
  const float inv = 0.02209708691207961f;  // 1/sqrt(2048)
  for (int b = gw; b < B_ROWS; b += nw) {
    const float* row = no + (size_t)b * D;
    float acc[TOPK] = {0,0,0,0,0};
#pragma unroll 2
    for (int i = 0; i < 8; ++i) {
      int off = i * 256 + lane * 4;
      f32x4 n4 = *(const f32x4*)(row + off);
#pragma unroll
      for (int j = 0; j < TOPK; ++j) {
        f32x4 kv = *(const f32x4*)(&kq[j*D + off]);
        acc[j] += n4[0]*kv[0] + n4[1]*kv[1] + n4[2]*kv[2] + n4[3]*kv[3];
      }
    }
    for (int off = 32; off; off >>= 1)
#pragma unroll
      for (int j = 0; j < TOPK; ++j) acc[j] += __shfl_xor(acc[j], off, 64);
    if (lane == 0) {
      float s[TOPK], mx = -INFINITY;
      for (int j = 0; j < TOPK; ++j) { s[j] = (acc[j] + sbias[j]) * inv * top_sims[j]; mx = fmaxf(mx, s[j]); }
      float sum = 0.f;
      for (int j = 0; j < TOPK; ++j) { s[j] = __expf(s[j] - mx); sum += s[j]; }
      float r = 1.0f / sum;
      for (int j = 0; j < TOPK; ++j) attn[(size_t)b*TOPK + j] = s[j] * r;
    }
  }
}

// ---------------- K6: GEMM no @ WgA^T (bf16 MFMA) + fused epilogue ----------------
#define BM 128
#define BN 128
#define BK 32
#define LDK (BK + 8)  // padded bf16 row stride (80 B, 16B-aligned)

__global__ __launch_bounds__(256) void k_gemm(
    const float* __restrict__ no, const float* __restrict__ Wg,
    const float* __restrict__ bg, const float* __restrict__ attn,
    const float* __restrict__ vb, const float* __restrict__ VW,
    float* __restrict__ out) {
  __shared__ unsigned short As[BM * LDK];
  __shared__ unsigned short Bs[BN * LDK];
  __shared__ float ep[2048];  // attn_l[640] | vw_l[640] | v_l[640] | bg_l[128]

  int tid = threadIdx.x;
  int lane = tid & 63, wid = tid >> 6;
  int brow = blockIdx.x * BM;
  int bcol = blockIdx.y * BN;
  int wr = wid >> 1, wc = wid & 1;

  f32x4 acc[4][4];
#pragma unroll
  for (int m = 0; m < 4; ++m)
#pragma unroll
    for (int n = 0; n < 4; ++n) acc[m][n] = (f32x4){0.f, 0.f, 0.f, 0.f};

  int fr = lane & 15, fg = lane >> 4;

  for (int kt = 0; kt < D / BK; ++kt) {
    int k0 = kt * BK;
#pragma unroll
    for (int i = 0; i < 4; ++i) {
      int fid = tid + i * 256;
      int row = fid >> 3, c4 = (fid & 7) * 4;
      f32x4 a4 = *(const f32x4*)(no + (size_t)(brow + row) * D + k0 + c4);
      f32x4 b4 = *(const f32x4*)(Wg + (size_t)(bcol + row) * (2 * D) + k0 + c4);
      u16x4 ab, bb;
      ab[0] = f2bf(a4[0]); ab[1] = f2bf(a4[1]); ab[2] = f2bf(a4[2]); ab[3] = f2bf(a4[3]);
      bb[0] = f2bf(b4[0]); bb[1] = f2bf(b4[1]); bb[2] = f2bf(b4[2]); bb[3] = f2bf(b4[3]);
      *(u16x4*)(&As[row * LDK + c4]) = ab;
      *(u16x4*)(&Bs[row * LDK + c4]) = bb;
    }
    __syncthreads();
    s16x8 af[4], bf[4];
#pragma unroll
    for (int m = 0; m < 4; ++m) af[m] = *(const s16x8*)(&As[(wr*64 + m*16 + fr) * LDK + fg*8]);
#pragma unroll
    for (int n = 0; n < 4; ++n) bf[n] = *(const s16x8*)(&Bs[(wc*64 + n*16 + fr) * LDK + fg*8]);
#pragma unroll
    for (int m = 0; m < 4; ++m)
#pragma unroll
      for (int n = 0; n < 4; ++n)
        acc[m][n] = __builtin_amdgcn_mfma_f32_16x16x32_bf16(af[m], bf[n], acc[m][n], 0, 0, 0);
    __syncthreads();
  }

  // stage epilogue rank-5 data
  for (int x = tid; x < 640; x += 256) ep[x] = attn[(size_t)brow * TOPK + x];          // attn rows
  for (int x = tid; x < 640; x += 256) { int j = x >> 7, c = x & 127; ep[640 + x]  = VW[j*D + bcol + c]; }
  for (int x = tid; x < 640; x += 256) { int j = x >> 7, c = x & 127; ep[1280 + x] = vb[j*D + bcol + c]; }
  if (tid < 128) ep[1920 + tid] = bg[bcol + tid];
  __syncthreads();

#pragma unroll
  for (int m = 0; m < 4; ++m) {
    int rbase = wr * 64 + m * 16 + fg * 4;
#pragma unroll
    for (int n = 0; n < 4; ++n) {
      int c = wc * 64 + n * 16 + fr;
      float vw0 = ep[640 + 0*128 + c], vw1 = ep[640 + 1*128 + c], vw2 = ep[640 + 2*128 + c],
            vw3 = ep[640 + 3*128 + c], vw4 = ep[640 + 4*128 + c];
      float v0 = ep[1280 + 0*128 + c], v1 = ep[1280 + 1*128 + c], v2 = ep[1280 + 2*128 + c],
            v3 = ep[1280 + 3*128 + c], v4 = ep[1280 + 4*128 + c];
      float bgc = ep[1920 + c];
#pragma unroll
      for (int i = 0; i < 4; ++i) {
        int r = rbase + i;
        float a0 = ep[r*5+0], a1 = ep[r*5+1], a2 = ep[r*5+2], a3 = ep[r*5+3], a4 = ep[r*5+4];
        float gl = acc[m][n][i] + bgc + a0*vw0 + a1*vw1 + a2*vw2 + a3*vw3 + a4*vw4;
        float att = a0*v0 + a1*v1 + a2*v2 + a3*v3 + a4*v4;
        float gate = 1.0f / (1.0f + __expf(-gl));
        size_t gi = (size_t)(brow + r) * D + bcol + c;
        out[gi] = no[gi] + gate * att;
      }
    }
  }
}

extern "C" void kernel_launch(void* const* d_in, const int* in_sizes, int n_in,
                              void* d_out, int out_size, void* d_ws, size_t ws_size,
                              hipStream_t stream) {
  (void)in_sizes; (void)n_in; (void)out_size; (void)ws_size;
  const float* no    = (const float*)d_in[0];
  const float* ce    = (const float*)d_in[1];
  const float* bank  = (const float*)d_in[2];
  const float* mvals = (const float*)d_in[3];
  const float* Wq    = (const float*)d_in[4];
  const float* bq    = (const float*)d_in[5];
  const float* Wk    = (const float*)d_in[6];
  const float* bk    = (const float*)d_in[7];
  const float* Wv    = (const float*)d_in[8];
  const float* bvp   = (const float*)d_in[9];
  const float* Wg    = (const float*)d_in[10];
  const float* bg    = (const float*)d_in[11];
  float* out = (float*)d_out;

  char* ws = (char*)d_ws;
  float* qn       = (float*)(ws + 0);        // 2048 f
  float* sims     = (float*)(ws + 8192);     // 50000 f
  float* top_sims = (float*)(ws + 208384);   // 5 f
  int*   top_idx  = (int*)  (ws + 208416);   // 5 i
  float* sbias    = (float*)(ws + 208448);   // 5 f
  float* kb       = (float*)(ws + 208512);   // 5*2048 f
  float* vb       = (float*)(ws + 249472);   // 5*2048 f
  float* KQ       = (float*)(ws + 290432);   // 5*2048 f
  float* VW       = (float*)(ws + 331392);   // 5*2048 f
  float* attn     = (float*)(ws + 372352);   // 16384*5 f  (ends at ~700 KB)

  k_qnorm<<<1, 256, 0, stream>>>(ce, qn);
  k_sims<<<1024, 256, 0, stream>>>(bank, qn, sims);
  k_topk<<<1, 256, 0, stream>>>(sims, top_sims, top_idx);
  k_kv<<<512, 256, 0, stream>>>(mvals, top_idx, Wk, bk, Wv, bvp, kb, vb);
  k_misc<<<8 + 512 + 1, 256, 0, stream>>>(Wq, bq, Wg, kb, vb, KQ, VW, sbias);
  k_attn<<<1024, 256, 0, stream>>>(no, KQ, sbias, top_sims, attn);
  k_gemm<<<dim3(B_ROWS / BM, D / BN), 256, 0, stream>>>(no, Wg, bg, attn, vb, VW, out);
}

// Round 2
// 845.236 us; speedup vs baseline: 1.5351x; 1.5351x over previous
//
#include <hip/hip_runtime.h>
#include <hip/hip_bf16.h>
#include <math.h>

#define D 2048
#define M_ROWS 50000
#define B_ROWS 16384
#define TOPK 5
#define EPSN 1e-12f

typedef __attribute__((ext_vector_type(4))) float f32x4;
typedef __attribute__((ext_vector_type(8))) short s16x8;
typedef __attribute__((ext_vector_type(4))) unsigned short u16x4;

__device__ __forceinline__ unsigned short f2bf(float f) {
  union { float f; unsigned int u; } x; x.f = f;
  unsigned int u = x.u;
  unsigned int r = u + 0x7fffu + ((u >> 16) & 1u);
  return (unsigned short)(r >> 16);
}

__device__ __forceinline__ void gload16(const void* g, void* l) {
  __builtin_amdgcn_global_load_lds(
      (const __attribute__((address_space(1))) unsigned int*)g,
      (__attribute__((address_space(3))) unsigned int*)l, 16, 0, 0);
}

// ---------------- K0: q_norm ----------------
__global__ void k_qnorm(const float* __restrict__ ce, float* __restrict__ qn) {
  __shared__ float red[256];
  int tid = threadIdx.x;
  float s = 0.f;
  for (int t = tid; t < D; t += 256) { float x = ce[t]; s += x * x; }
  red[tid] = s; __syncthreads();
  for (int w = 128; w > 0; w >>= 1) { if (tid < w) red[tid] += red[tid + w]; __syncthreads(); }
  float inv = 1.0f / fmaxf(sqrtf(red[0]), EPSN);
  for (int t = tid; t < D; t += 256) qn[t] = ce[t] * inv;
}

// ---------------- K1: sims over memory bank ----------------
__global__ void k_sims(const float* __restrict__ bank, const float* __restrict__ qn,
                       float* __restrict__ sims) {
  __shared__ float qs[D];
  int tid = threadIdx.x;
  for (int t = tid; t < D; t += 256) qs[t] = qn[t];
  __syncthreads();
  int lane = tid & 63, wid = tid >> 6;
  int gw = (blockIdx.x << 2) + wid;
  int nw = gridDim.x << 2;
  for (int m = gw; m < M_ROWS; m += nw) {
    const float* row = bank + (size_t)m * D;
    float dot = 0.f, sq = 0.f;
#pragma unroll
    for (int i = 0; i < 8; ++i) {
      int off = i * 256 + lane * 4;
      f32x4 a = *(const f32x4*)(row + off);
      f32x4 q = *(const f32x4*)(qs + off);
      dot += a[0]*q[0] + a[1]*q[1] + a[2]*q[2] + a[3]*q[3];
      sq  += a[0]*a[0] + a[1]*a[1] + a[2]*a[2] + a[3]*a[3];
    }
    for (int off = 32; off; off >>= 1) {
      dot += __shfl_xor(dot, off, 64);
      sq  += __shfl_xor(sq,  off, 64);
    }
    if (lane == 0) sims[m] = dot / fmaxf(sqrtf(sq), EPSN);
  }
}

// ---------------- K2: top-5 ----------------
__global__ void k_topk(const float* __restrict__ sims, float* __restrict__ top_sims,
                       int* __restrict__ top_idx) {
  __shared__ float sval[256 * TOPK];
  __shared__ int   sidx[256 * TOPK];
  int tid = threadIdx.x;
  float lv[TOPK]; int li[TOPK];
#pragma unroll
  for (int j = 0; j < TOPK; ++j) { lv[j] = -INFINITY; li[j] = 0x7fffffff; }
  for (int m = tid; m < M_ROWS; m += 256) {
    float v = sims[m];
    if (v > lv[TOPK-1] || (v == lv[TOPK-1] && m < li[TOPK-1])) {
      lv[TOPK-1] = v; li[TOPK-1] = m;
#pragma unroll
      for (int j = TOPK-1; j > 0; --j) {
        bool sw = (lv[j] > lv[j-1]) || (lv[j] == lv[j-1] && li[j] < li[j-1]);
        if (sw) { float tv=lv[j]; lv[j]=lv[j-1]; lv[j-1]=tv; int ti=li[j]; li[j]=li[j-1]; li[j-1]=ti; }
      }
    }
  }
#pragma unroll
  for (int j = 0; j < TOPK; ++j) { sval[tid*TOPK+j] = lv[j]; sidx[tid*TOPK+j] = li[j]; }
  __syncthreads();
  if (tid == 0) {
    float bvv[TOPK]; int bii[TOPK];
    for (int j = 0; j < TOPK; ++j) { bvv[j] = -INFINITY; bii[j] = 0x7fffffff; }
    for (int c = 0; c < 256 * TOPK; ++c) {
      float v = sval[c]; int i = sidx[c];
      if (v > bvv[TOPK-1] || (v == bvv[TOPK-1] && i < bii[TOPK-1])) {
        bvv[TOPK-1] = v; bii[TOPK-1] = i;
        for (int j = TOPK-1; j > 0; --j) {
          bool sw = (bvv[j] > bvv[j-1]) || (bvv[j] == bvv[j-1] && bii[j] < bii[j-1]);
          if (sw) { float tv=bvv[j]; bvv[j]=bvv[j-1]; bvv[j-1]=tv; int ti=bii[j]; bii[j]=bii[j-1]; bii[j-1]=ti; }
        }
      }
    }
    for (int j = 0; j < TOPK; ++j) { top_sims[j] = bvv[j]; top_idx[j] = bii[j]; }
  }
}

// ---------------- K3: k,v = memories @ Wk/Wv^T + b ----------------
__global__ void k_kv(const float* __restrict__ mvals, const int* __restrict__ top_idx,
                     const float* __restrict__ Wk, const float* __restrict__ bk,
                     const float* __restrict__ Wv, const float* __restrict__ bvp,
                     float* __restrict__ kb, float* __restrict__ vb) {
  __shared__ float mem[TOPK][D];
  int tid = threadIdx.x;
  for (int j = 0; j < TOPK; ++j) {
    const float* src = mvals + (size_t)top_idx[j] * D;
    for (int t = tid; t < D; t += 256) mem[j][t] = src[t];
  }
  __syncthreads();
  int lane = tid & 63, wid = tid >> 6;
  int c = blockIdx.x * 4 + wid;
  const float* wkr = Wk + (size_t)c * D;
  const float* wvr = Wv + (size_t)c * D;
  float ak[TOPK] = {0,0,0,0,0}, av[TOPK] = {0,0,0,0,0};
#pragma unroll 2
  for (int i = 0; i < 8; ++i) {
    int off = i * 256 + lane * 4;
    f32x4 wk4 = *(const f32x4*)(wkr + off);
    f32x4 wv4 = *(const f32x4*)(wvr + off);
#pragma unroll
    for (int j = 0; j < TOPK; ++j) {
      f32x4 mv = *(const f32x4*)(&mem[j][off]);
      ak[j] += mv[0]*wk4[0] + mv[1]*wk4[1] + mv[2]*wk4[2] + mv[3]*wk4[3];
      av[j] += mv[0]*wv4[0] + mv[1]*wv4[1] + mv[2]*wv4[2] + mv[3]*wv4[3];
    }
  }
  for (int off = 32; off; off >>= 1) {
#pragma unroll
    for (int j = 0; j < TOPK; ++j) {
      ak[j] += __shfl_xor(ak[j], off, 64);
      av[j] += __shfl_xor(av[j], off, 64);
    }
  }
  if (lane == 0) {
#pragma unroll
    for (int j = 0; j < TOPK; ++j) { kb[j*D + c] = ak[j] + bk[c]; vb[j*D + c] = av[j] + bvp[c]; }
  }
}

// ---------------- K4: prep — KQ partials, VW, sbias, WgA bf16 cast ----------------
// grid: [0,64) KQ partials, [64,576) VW, 576 sbias, [577,1089) castB (fast path only)
__global__ void k_prep(const float* __restrict__ Wq, const float* __restrict__ bq,
                       const float* __restrict__ Wg,
                       const float* __restrict__ kb, const float* __restrict__ vb,
                       float* __restrict__ KQpart, float* __restrict__ VW,
                       float* __restrict__ sbias, unsigned short* __restrict__ B_sw) {
  __shared__ float sh[TOPK * D];
  int tid = threadIdx.x;
  int bid = blockIdx.x;
  if (bid < 64) {
    // KQpart[cc][j][t] = sum_{c in chunk cc} kb[j,c] * Wq[c,t]
    int cc = bid >> 3, tc = bid & 7;
    for (int x = tid; x < TOPK * 256; x += 256) sh[x] = kb[(x >> 8) * D + cc * 256 + (x & 255)];
    __syncthreads();
    float acc[TOPK] = {0,0,0,0,0};
    const float* wq = Wq + (size_t)(cc * 256) * D + tc * 256 + tid;
#pragma unroll 4
    for (int c = 0; c < 256; ++c) {
      float w = wq[(size_t)c * D];
#pragma unroll
      for (int j = 0; j < TOPK; ++j) acc[j] += sh[j * 256 + c] * w;
    }
#pragma unroll
    for (int j = 0; j < TOPK; ++j)
      KQpart[(size_t)(cc * TOPK + j) * D + tc * 256 + tid] = acc[j];
  } else if (bid < 576) {
    // VW[j,c] = sum_t v[j,t] * Wg[c, D+t]
    for (int x = tid; x < TOPK * D; x += 256) sh[x] = vb[x];
    __syncthreads();
    int lane = tid & 63, wid = tid >> 6;
    int c = (bid - 64) * 4 + wid;
    const float* wg = Wg + (size_t)c * (2 * D) + D;
    float acc[TOPK] = {0,0,0,0,0};
#pragma unroll 2
    for (int i = 0; i < 8; ++i) {
      int off = i * 256 + lane * 4;
      f32x4 g4 = *(const f32x4*)(wg + off);
#pragma unroll
      for (int j = 0; j < TOPK; ++j) {
        f32x4 vv = *(const f32x4*)(&sh[j*D + off]);
        acc[j] += vv[0]*g4[0] + vv[1]*g4[1] + vv[2]*g4[2] + vv[3]*g4[3];
      }
    }
    for (int off = 32; off; off >>= 1)
#pragma unroll
      for (int j = 0; j < TOPK; ++j) acc[j] += __shfl_xor(acc[j], off, 64);
    if (lane == 0)
      for (int j = 0; j < TOPK; ++j) VW[j*D + c] = acc[j];
  } else if (bid == 576) {
    for (int j = 0; j < TOPK; ++j) {
      float s = 0.f;
      for (int t = tid; t < D; t += 256) s += bq[t] * kb[j*D + t];
      sh[tid] = s; __syncthreads();
      for (int w = 128; w > 0; w >>= 1) { if (tid < w) sh[tid] += sh[tid + w]; __syncthreads(); }
      if (tid == 0) sbias[j] = sh[0];
      __syncthreads();
    }
  } else {
    // castB: B_sw[r][ (chunk^(r&7)) within 64-col block ] = bf16(Wg[r][col]), cols 0..2047
    int base = (bid - 577) * 1024;
#pragma unroll
    for (int it = 0; it < 4; ++it) {
      int id = base + it * 256 + tid;      // 0..524287
      int r = id >> 8;
      int cidx = id & 255;
      int kb_ = cidx >> 3, c = cidx & 7;
      const float* src = Wg + (size_t)r * (2 * D) + kb_ * 64 + c * 8;
      f32x4 a = *(const f32x4*)(src);
      f32x4 b = *(const f32x4*)(src + 4);
      s16x8 p;
      p[0]=(short)f2bf(a[0]); p[1]=(short)f2bf(a[1]); p[2]=(short)f2bf(a[2]); p[3]=(short)f2bf(a[3]);
      p[4]=(short)f2bf(b[0]); p[5]=(short)f2bf(b[1]); p[6]=(short)f2bf(b[2]); p[7]=(short)f2bf(b[3]);
      int dst = kb_ * 64 + ((c ^ (r & 7)) * 8);
      *(s16x8*)(B_sw + (size_t)r * D + dst) = p;
    }
  }
}

// ---------------- K5: scores + softmax -> attn[B][5]; optional fused no->bf16 cast ----------------
template <bool WRITE_CAST>
__global__ void k_attn(const float* __restrict__ no, const float* __restrict__ KQpart,
                       const float* __restrict__ sbias, const float* __restrict__ top_sims,
                       float* __restrict__ attn, unsigned short* __restrict__ A_sw) {
  __shared__ float kq[TOPK * D];
  int tid = threadIdx.x;
  for (int x = tid; x < TOPK * D; x += 256) {
    float s = 0.f;
#pragma unroll
    for (int cc = 0; cc < 8; ++cc) s += KQpart[(size_t)cc * TOPK * D + x];
    kq[x] = s;
  }
  __syncthreads();
  int lane = tid & 63, wid = tid >> 6;
  int gw = blockIdx.x * 4 + wid, nw = gridDim.x * 4;
  const float inv = 0.02209708691207961f;  // 1/sqrt(2048)
  for (int b = gw; b < B_ROWS; b += nw) {
    const float* row = no + (size_t)b * D;
    float acc[TOPK] = {0,0,0,0,0};
    int swz = (b & 7) << 4;
#pragma unroll 2
    for (int i = 0; i < 8; ++i) {
      int off = i * 256 + lane * 4;
      f32x4 n4 = *(const f32x4*)(row + off);
#pragma unroll
      for (int j = 0; j < TOPK; ++j) {
        f32x4 kv = *(const f32x4*)(&kq[j*D + off]);
        acc[j] += n4[0]*kv[0] + n4[1]*kv[1] + n4[2]*kv[2] + n4[3]*kv[3];
      }
      if (WRITE_CAST) {
        u16x4 c4;
        c4[0]=f2bf(n4[0]); c4[1]=f2bf(n4[1]); c4[2]=f2bf(n4[2]); c4[3]=f2bf(n4[3]);
        int bytecol = off * 2;
        *(u16x4*)((char*)A_sw + (size_t)b * (D*2) + (bytecol ^ swz)) = c4;
      }
    }
    for (int off = 32; off; off >>= 1)
#pragma unroll
      for (int j = 0; j < TOPK; ++j) acc[j] += __shfl_xor(acc[j], off, 64);
    if (lane == 0) {
      float s[TOPK], mx = -INFINITY;
      for (int j = 0; j < TOPK; ++j) { s[j] = (acc[j] + sbias[j]) * inv * top_sims[j]; mx = fmaxf(mx, s[j]); }
      float sum = 0.f;
      for (int j = 0; j < TOPK; ++j) { s[j] = __expf(s[j] - mx); sum += s[j]; }
      float r = 1.0f / sum;
      for (int j = 0; j < TOPK; ++j) attn[(size_t)b*TOPK + j] = s[j] * r;
    }
  }
}

// ---------------- K6 (fast): bf16 MFMA GEMM with global_load_lds + swizzled LDS ----------------
__global__ __launch_bounds__(256) void k_gemm_bf(
    const unsigned short* __restrict__ A_sw, const unsigned short* __restrict__ B_sw,
    const float* __restrict__ no, const float* __restrict__ bg,
    const float* __restrict__ attn, const float* __restrict__ vb,
    const float* __restrict__ VW, float* __restrict__ out) {
  __shared__ unsigned short As[128 * 64];
  __shared__ unsigned short Bs[128 * 64];
  __shared__ float ep[2048];  // attn[640] | vw[640] | v[640] | bg[128]

  int tid = threadIdx.x;
  int lane = tid & 63, wid = tid >> 6;
  int fr = lane & 15, fg = lane >> 4;
  int wr = wid >> 1, wc = wid & 1;

  // XCD-bijective swizzle over 2048 tiles; n-fast within a chunk
  int id = blockIdx.x;
  int tile = (id & 7) * 256 + (id >> 3);
  int mt = tile >> 4, nt = tile & 15;
  int brow = mt * 128, bcol = nt * 128;

  f32x4 acc[4][4];
#pragma unroll
  for (int m = 0; m < 4; ++m)
#pragma unroll
    for (int n = 0; n < 4; ++n) acc[m][n] = (f32x4){0.f, 0.f, 0.f, 0.f};

  // staging pointers: chunkid = i*256 + tid; row = cid>>3, chunk-in-row = cid&7
  const unsigned short* gA[4];
  const unsigned short* gB[4];
  unsigned short* lA[4];
  unsigned short* lB[4];
#pragma unroll
  for (int i = 0; i < 4; ++i) {
    int cid = i * 256 + tid;
    int row = cid >> 3, cc = cid & 7;
    gA[i] = A_sw + (size_t)(brow + row) * D + cc * 8;
    gB[i] = B_sw + (size_t)(bcol + row) * D + cc * 8;
    int base = (i * 256 + wid * 64) * 8;   // wave-uniform LDS chunk base (elems)
    lA[i] = As + base;
    lB[i] = Bs + base;
  }

  for (int kt = 0; kt < D / 64; ++kt) {
#pragma unroll
    for (int i = 0; i < 4; ++i) { gload16(gA[i], lA[i]); gload16(gB[i], lB[i]); }
#pragma unroll
    for (int i = 0; i < 4; ++i) { gA[i] += 64; gB[i] += 64; }
    __syncthreads();
#pragma unroll
    for (int kk = 0; kk < 2; ++kk) {
      s16x8 af[4], bfr[4];
#pragma unroll
      for (int m = 0; m < 4; ++m) {
        int row = wr * 64 + m * 16 + fr;
        int addr = row * 128 + ((kk * 64 + fg * 16) ^ ((row & 7) << 4));
        af[m] = *(const s16x8*)((const char*)As + addr);
      }
#pragma unroll
      for (int n = 0; n < 4; ++n) {
        int row = wc * 64 + n * 16 + fr;
        int addr = row * 128 + ((kk * 64 + fg * 16) ^ ((row & 7) << 4));
        bfr[n] = *(const s16x8*)((const char*)Bs + addr);
      }
#pragma unroll
      for (int m = 0; m < 4; ++m)
#pragma unroll
        for (int n = 0; n < 4; ++n)
          acc[m][n] = __builtin_amdgcn_mfma_f32_16x16x32_bf16(af[m], bfr[n], acc[m][n], 0, 0, 0);
    }
    __syncthreads();
  }

  // epilogue staging
  for (int x = tid; x < 640; x += 256) ep[x] = attn[(size_t)brow * TOPK + x];
  for (int x = tid; x < 640; x += 256) { int j = x >> 7, c = x & 127; ep[640 + x]  = VW[j*D + bcol + c]; }
  for (int x = tid; x < 640; x += 256) { int j = x >> 7, c = x & 127; ep[1280 + x] = vb[j*D + bcol + c]; }
  if (tid < 128) ep[1920 + tid] = bg[bcol + tid];
  __syncthreads();

#pragma unroll
  for (int m = 0; m < 4; ++m) {
    int rbase = wr * 64 + m * 16 + fg * 4;
#pragma unroll
    for (int n = 0; n < 4; ++n) {
      int c = wc * 64 + n * 16 + fr;
      float vw0 = ep[640 + 0*128 + c], vw1 = ep[640 + 1*128 + c], vw2 = ep[640 + 2*128 + c],
            vw3 = ep[640 + 3*128 + c], vw4 = ep[640 + 4*128 + c];
      float v0 = ep[1280 + 0*128 + c], v1 = ep[1280 + 1*128 + c], v2 = ep[1280 + 2*128 + c],
            v3 = ep[1280 + 3*128 + c], v4 = ep[1280 + 4*128 + c];
      float bgc = ep[1920 + c];
#pragma unroll
      for (int i = 0; i < 4; ++i) {
        int r = rbase + i;
        float a0 = ep[r*5+0], a1 = ep[r*5+1], a2 = ep[r*5+2], a3 = ep[r*5+3], a4 = ep[r*5+4];
        float gl = acc[m][n][i] + bgc + a0*vw0 + a1*vw1 + a2*vw2 + a3*vw3 + a4*vw4;
        float att = a0*v0 + a1*v1 + a2*v2 + a3*v3 + a4*v4;
        float gate = 1.0f / (1.0f + __expf(-gl));
        size_t gi = (size_t)(brow + r) * D + bcol + c;
        out[gi] = no[gi] + gate * att;
      }
    }
  }
}

// ---------------- K6 (fallback): round-1 f32-staging GEMM ----------------
#define BM 128
#define BN 128
#define BKf 32
#define LDK (BKf + 8)

__global__ __launch_bounds__(256) void k_gemm_f32(
    const float* __restrict__ no, const float* __restrict__ Wg,
    const float* __restrict__ bg, const float* __restrict__ attn,
    const float* __restrict__ vb, const float* __restrict__ VW,
    float* __restrict__ out) {
  __shared__ unsigned short As[BM * LDK];
  __shared__ unsigned short Bs[BN * LDK];
  __shared__ float ep[2048];

  int tid = threadIdx.x;
  int lane = tid & 63, wid = tid >> 6;
  int brow = blockIdx.x * BM;
  int bcol = blockIdx.y * BN;
  int wr = wid >> 1, wc = wid & 1;

  f32x4 acc[4][4];
#pragma unroll
  for (int m = 0; m < 4; ++m)
#pragma unroll
    for (int n = 0; n < 4; ++n) acc[m][n] = (f32x4){0.f, 0.f, 0.f, 0.f};

  int fr = lane & 15, fg = lane >> 4;

  for (int kt = 0; kt < D / BKf; ++kt) {
    int k0 = kt * BKf;
#pragma unroll
    for (int i = 0; i < 4; ++i) {
      int fid = tid + i * 256;
      int row = fid >> 3, c4 = (fid & 7) * 4;
      f32x4 a4 = *(const f32x4*)(no + (size_t)(brow + row) * D + k0 + c4);
      f32x4 b4 = *(const f32x4*)(Wg + (size_t)(bcol + row) * (2 * D) + k0 + c4);
      u16x4 ab, bb;
      ab[0] = f2bf(a4[0]); ab[1] = f2bf(a4[1]); ab[2] = f2bf(a4[2]); ab[3] = f2bf(a4[3]);
      bb[0] = f2bf(b4[0]); bb[1] = f2bf(b4[1]); bb[2] = f2bf(b4[2]); bb[3] = f2bf(b4[3]);
      *(u16x4*)(&As[row * LDK + c4]) = ab;
      *(u16x4*)(&Bs[row * LDK + c4]) = bb;
    }
    __syncthreads();
    s16x8 af[4], bfr[4];
#pragma unroll
    for (int m = 0; m < 4; ++m) af[m] = *(const s16x8*)(&As[(wr*64 + m*16 + fr) * LDK + fg*8]);
#pragma unroll
    for (int n = 0; n < 4; ++n) bfr[n] = *(const s16x8*)(&Bs[(wc*64 + n*16 + fr) * LDK + fg*8]);
#pragma unroll
    for (int m = 0; m < 4; ++m)
#pragma unroll
      for (int n = 0; n < 4; ++n)
        acc[m][n] = __builtin_amdgcn_mfma_f32_16x16x32_bf16(af[m], bfr[n], acc[m][n], 0, 0, 0);
    __syncthreads();
  }

  for (int x = tid; x < 640; x += 256) ep[x] = attn[(size_t)brow * TOPK + x];
  for (int x = tid; x < 640; x += 256) { int j = x >> 7, c = x & 127; ep[640 + x]  = VW[j*D + bcol + c]; }
  for (int x = tid; x < 640; x += 256) { int j = x >> 7, c = x & 127; ep[1280 + x] = vb[j*D + bcol + c]; }
  if (tid < 128) ep[1920 + tid] = bg[bcol + tid];
  __syncthreads();

#pragma unroll
  for (int m = 0; m < 4; ++m) {
    int rbase = wr * 64 + m * 16 + fg * 4;
#pragma unroll
    for (int n = 0; n < 4; ++n) {
      int c = wc * 64 + n * 16 + fr;
      float vw0 = ep[640 + 0*128 + c], vw1 = ep[640 + 1*128 + c], vw2 = ep[640 + 2*128 + c],
            vw3 = ep[640 + 3*128 + c], vw4 = ep[640 + 4*128 + c];
      float v0 = ep[1280 + 0*128 + c], v1 = ep[1280 + 1*128 + c], v2 = ep[1280 + 2*128 + c],
            v3 = ep[1280 + 3*128 + c], v4 = ep[1280 + 4*128 + c];
      float bgc = ep[1920 + c];
#pragma unroll
      for (int i = 0; i < 4; ++i) {
        int r = rbase + i;
        float a0 = ep[r*5+0], a1 = ep[r*5+1], a2 = ep[r*5+2], a3 = ep[r*5+3], a4 = ep[r*5+4];
        float gl = acc[m][n][i] + bgc + a0*vw0 + a1*vw1 + a2*vw2 + a3*vw3 + a4*vw4;
        float att = a0*v0 + a1*v1 + a2*v2 + a3*v3 + a4*v4;
        float gate = 1.0f / (1.0f + __expf(-gl));
        size_t gi = (size_t)(brow + r) * D + bcol + c;
        out[gi] = no[gi] + gate * att;
      }
    }
  }
}

extern "C" void kernel_launch(void* const* d_in, const int* in_sizes, int n_in,
                              void* d_out, int out_size, void* d_ws, size_t ws_size,
                              hipStream_t stream) {
  (void)in_sizes; (void)n_in; (void)out_size;
  const float* no    = (const float*)d_in[0];
  const float* ce    = (const float*)d_in[1];
  const float* bank  = (const float*)d_in[2];
  const float* mvals = (const float*)d_in[3];
  const float* Wq    = (const float*)d_in[4];
  const float* bq    = (const float*)d_in[5];
  const float* Wk    = (const float*)d_in[6];
  const float* bk    = (const float*)d_in[7];
  const float* Wv    = (const float*)d_in[8];
  const float* bvp   = (const float*)d_in[9];
  const float* Wg    = (const float*)d_in[10];
  const float* bg    = (const float*)d_in[11];
  float* out = (float*)d_out;

  char* ws = (char*)d_ws;
  float* qn       = (float*)(ws + 0);
  float* sims     = (float*)(ws + 16384);
  float* top_sims = (float*)(ws + 220160);
  int*   top_idx  = (int*)  (ws + 220192);
  float* sbias    = (float*)(ws + 220224);
  float* kb       = (float*)(ws + 221184);
  float* vb       = (float*)(ws + 262144);
  float* VW       = (float*)(ws + 303104);
  float* KQpart   = (float*)(ws + 344064);   // 8*5*2048 f = 327680 B
  float* attn     = (float*)(ws + 671744);   // 16384*5 f = 327680 B -> ends 999424
  unsigned short* A_sw = (unsigned short*)(ws + 1048576);    // 64 MB
  unsigned short* B_sw = (unsigned short*)(ws + 1048576 + (size_t)B_ROWS * D * 2);  // 8 MB

  const size_t ws_need = 1048576 + (size_t)B_ROWS * D * 2 + (size_t)D * D * 2;
  const bool fast = ws_size >= ws_need;

  k_qnorm<<<1, 256, 0, stream>>>(ce, qn);
  k_sims<<<1024, 256, 0, stream>>>(bank, qn, sims);
  k_topk<<<1, 256, 0, stream>>>(sims, top_sims, top_idx);
  k_kv<<<512, 256, 0, stream>>>(mvals, top_idx, Wk, bk, Wv, bvp, kb, vb);
  k_prep<<<fast ? 1089 : 577, 256, 0, stream>>>(Wq, bq, Wg, kb, vb, KQpart, VW, sbias, B_sw);
  if (fast) {
    k_attn<true><<<1024, 256, 0, stream>>>(no, KQpart, sbias, top_sims, attn, A_sw);
    k_gemm_bf<<<2048, 256, 0, stream>>>(A_sw, B_sw, no, bg, attn, vb, VW, out);
  } else {
    k_attn<false><<<1024, 256, 0, stream>>>(no, KQpart, sbias, top_sims, attn, A_sw);
    k_gemm_f32<<<dim3(B_ROWS / BM, D / BN), 256, 0, stream>>>(no, Wg, bg, attn, vb, VW, out);
  }
}

// Round 4
// 661.213 us; speedup vs baseline: 1.9623x; 1.2783x over previous
//
#include <hip/hip_runtime.h>
#include <hip/hip_bf16.h>
#include <math.h>

#define D 2048
#define M_ROWS 50000
#define B_ROWS 16384
#define TOPK 5
#define EPSN 1e-12f

typedef __attribute__((ext_vector_type(4))) float f32x4;
typedef __attribute__((ext_vector_type(8))) short s16x8;
typedef __attribute__((ext_vector_type(4))) unsigned short u16x4;

__device__ __forceinline__ unsigned short f2bf(float f) {
  union { float f; unsigned int u; } x; x.f = f;
  unsigned int u = x.u;
  unsigned int r = u + 0x7fffu + ((u >> 16) & 1u);
  return (unsigned short)(r >> 16);
}

__device__ __forceinline__ void gload16(const void* g, void* l) {
  __builtin_amdgcn_global_load_lds(
      (const __attribute__((address_space(1))) unsigned int*)g,
      (__attribute__((address_space(3))) unsigned int*)l, 16, 0, 0);
}

// ---------------- K0: q_norm ----------------
__global__ void k_qnorm(const float* __restrict__ ce, float* __restrict__ qn) {
  __shared__ float red[256];
  int tid = threadIdx.x;
  float s = 0.f;
  for (int t = tid; t < D; t += 256) { float x = ce[t]; s += x * x; }
  red[tid] = s; __syncthreads();
  for (int w = 128; w > 0; w >>= 1) { if (tid < w) red[tid] += red[tid + w]; __syncthreads(); }
  float inv = 1.0f / fmaxf(sqrtf(red[0]), EPSN);
  for (int t = tid; t < D; t += 256) qn[t] = ce[t] * inv;
}

// ---------------- K1: sims over memory bank ----------------
__global__ void k_sims(const float* __restrict__ bank, const float* __restrict__ qn,
                       float* __restrict__ sims) {
  __shared__ float qs[D];
  int tid = threadIdx.x;
  for (int t = tid; t < D; t += 256) qs[t] = qn[t];
  __syncthreads();
  int lane = tid & 63, wid = tid >> 6;
  int gw = (blockIdx.x << 2) + wid;
  int nw = gridDim.x << 2;
  for (int m = gw; m < M_ROWS; m += nw) {
    const float* row = bank + (size_t)m * D;
    float dot = 0.f, sq = 0.f;
#pragma unroll
    for (int i = 0; i < 8; ++i) {
      int off = i * 256 + lane * 4;
      f32x4 a = *(const f32x4*)(row + off);
      f32x4 q = *(const f32x4*)(qs + off);
      dot += a[0]*q[0] + a[1]*q[1] + a[2]*q[2] + a[3]*q[3];
      sq  += a[0]*a[0] + a[1]*a[1] + a[2]*a[2] + a[3]*a[3];
    }
    for (int off = 32; off; off >>= 1) {
      dot += __shfl_xor(dot, off, 64);
      sq  += __shfl_xor(sq,  off, 64);
    }
    if (lane == 0) sims[m] = dot / fmaxf(sqrtf(sq), EPSN);
  }
}

// ---------------- K2: top-5 ----------------
__global__ void k_topk(const float* __restrict__ sims, float* __restrict__ top_sims,
                       int* __restrict__ top_idx) {
  __shared__ float sval[256 * TOPK];
  __shared__ int   sidx[256 * TOPK];
  __shared__ float sv2[64 * TOPK];
  __shared__ int   si2[64 * TOPK];
  int tid = threadIdx.x;
  float lv[TOPK]; int li[TOPK];
#pragma unroll
  for (int j = 0; j < TOPK; ++j) { lv[j] = -INFINITY; li[j] = 0x7fffffff; }
  for (int m = tid; m < M_ROWS; m += 256) {
    float v = sims[m];
    if (v > lv[TOPK-1] || (v == lv[TOPK-1] && m < li[TOPK-1])) {
      lv[TOPK-1] = v; li[TOPK-1] = m;
#pragma unroll
      for (int j = TOPK-1; j > 0; --j) {
        bool sw = (lv[j] > lv[j-1]) || (lv[j] == lv[j-1] && li[j] < li[j-1]);
        if (sw) { float tv=lv[j]; lv[j]=lv[j-1]; lv[j-1]=tv; int ti=li[j]; li[j]=li[j-1]; li[j-1]=ti; }
      }
    }
  }
#pragma unroll
  for (int j = 0; j < TOPK; ++j) { sval[tid*TOPK+j] = lv[j]; sidx[tid*TOPK+j] = li[j]; }
  __syncthreads();
  if (tid < 64) {
    float bv[TOPK]; int bi[TOPK];
    for (int j = 0; j < TOPK; ++j) { bv[j] = -INFINITY; bi[j] = 0x7fffffff; }
    for (int c = tid * 20; c < tid * 20 + 20; ++c) {
      float v = sval[c]; int i = sidx[c];
      if (v > bv[TOPK-1] || (v == bv[TOPK-1] && i < bi[TOPK-1])) {
        bv[TOPK-1] = v; bi[TOPK-1] = i;
        for (int j = TOPK-1; j > 0; --j) {
          bool sw = (bv[j] > bv[j-1]) || (bv[j] == bv[j-1] && bi[j] < bi[j-1]);
          if (sw) { float tv=bv[j]; bv[j]=bv[j-1]; bv[j-1]=tv; int ti=bi[j]; bi[j]=bi[j-1]; bi[j-1]=ti; }
        }
      }
    }
    for (int j = 0; j < TOPK; ++j) { sv2[tid*TOPK+j] = bv[j]; si2[tid*TOPK+j] = bi[j]; }
  }
  __syncthreads();
  if (tid == 0) {
    float bvv[TOPK]; int bii[TOPK];
    for (int j = 0; j < TOPK; ++j) { bvv[j] = -INFINITY; bii[j] = 0x7fffffff; }
    for (int c = 0; c < 64 * TOPK; ++c) {
      float v = sv2[c]; int i = si2[c];
      if (v > bvv[TOPK-1] || (v == bvv[TOPK-1] && i < bii[TOPK-1])) {
        bvv[TOPK-1] = v; bii[TOPK-1] = i;
        for (int j = TOPK-1; j > 0; --j) {
          bool sw = (bvv[j] > bvv[j-1]) || (bvv[j] == bvv[j-1] && bii[j] < bii[j-1]);
          if (sw) { float tv=bvv[j]; bvv[j]=bvv[j-1]; bvv[j-1]=tv; int ti=bii[j]; bii[j]=bii[j-1]; bii[j-1]=ti; }
        }
      }
    }
    for (int j = 0; j < TOPK; ++j) { top_sims[j] = bvv[j]; top_idx[j] = bii[j]; }
  }
}

// ---------------- K3: k,v = memories @ Wk/Wv^T + b ----------------
__global__ void k_kv(const float* __restrict__ mvals, const int* __restrict__ top_idx,
                     const float* __restrict__ Wk, const float* __restrict__ bk,
                     const float* __restrict__ Wv, const float* __restrict__ bvp,
                     float* __restrict__ kb, float* __restrict__ vb) {
  __shared__ float mem[TOPK][D];
  int tid = threadIdx.x;
  for (int j = 0; j < TOPK; ++j) {
    const float* src = mvals + (size_t)top_idx[j] * D;
    for (int t = tid; t < D; t += 256) mem[j][t] = src[t];
  }
  __syncthreads();
  int lane = tid & 63, wid = tid >> 6;
  int c = blockIdx.x * 4 + wid;
  const float* wkr = Wk + (size_t)c * D;
  const float* wvr = Wv + (size_t)c * D;
  float ak[TOPK] = {0,0,0,0,0}, av[TOPK] = {0,0,0,0,0};
#pragma unroll 2
  for (int i = 0; i < 8; ++i) {
    int off = i * 256 + lane * 4;
    f32x4 wk4 = *(const f32x4*)(wkr + off);
    f32x4 wv4 = *(const f32x4*)(wvr + off);
#pragma unroll
    for (int j = 0; j < TOPK; ++j) {
      f32x4 mv = *(const f32x4*)(&mem[j][off]);
      ak[j] += mv[0]*wk4[0] + mv[1]*wk4[1] + mv[2]*wk4[2] + mv[3]*wk4[3];
      av[j] += mv[0]*wv4[0] + mv[1]*wv4[1] + mv[2]*wv4[2] + mv[3]*wv4[3];
    }
  }
  for (int off = 32; off; off >>= 1) {
#pragma unroll
    for (int j = 0; j < TOPK; ++j) {
      ak[j] += __shfl_xor(ak[j], off, 64);
      av[j] += __shfl_xor(av[j], off, 64);
    }
  }
  if (lane == 0) {
#pragma unroll
    for (int j = 0; j < TOPK; ++j) { kb[j*D + c] = ak[j] + bk[c]; vb[j*D + c] = av[j] + bvp[c]; }
  }
}

// ---------------- K4: prep — KQ partials, VW, sbias, WgA bf16 cast ----------------
__global__ void k_prep(const float* __restrict__ Wq, const float* __restrict__ bq,
                       const float* __restrict__ Wg,
                       const float* __restrict__ kb, const float* __restrict__ vb,
                       float* __restrict__ KQpart, float* __restrict__ VW,
                       float* __restrict__ sbias, unsigned short* __restrict__ B_sw) {
  __shared__ float sh[TOPK * D];
  int tid = threadIdx.x;
  int bid = blockIdx.x;
  if (bid < 64) {
    int cc = bid >> 3, tc = bid & 7;
    for (int x = tid; x < TOPK * 256; x += 256) sh[x] = kb[(x >> 8) * D + cc * 256 + (x & 255)];
    __syncthreads();
    float acc[TOPK] = {0,0,0,0,0};
    const float* wq = Wq + (size_t)(cc * 256) * D + tc * 256 + tid;
#pragma unroll 4
    for (int c = 0; c < 256; ++c) {
      float w = wq[(size_t)c * D];
#pragma unroll
      for (int j = 0; j < TOPK; ++j) acc[j] += sh[j * 256 + c] * w;
    }
#pragma unroll
    for (int j = 0; j < TOPK; ++j)
      KQpart[(size_t)(cc * TOPK + j) * D + tc * 256 + tid] = acc[j];
  } else if (bid < 576) {
    for (int x = tid; x < TOPK * D; x += 256) sh[x] = vb[x];
    __syncthreads();
    int lane = tid & 63, wid = tid >> 6;
    int c = (bid - 64) * 4 + wid;
    const float* wg = Wg + (size_t)c * (2 * D) + D;
    float acc[TOPK] = {0,0,0,0,0};
#pragma unroll 2
    for (int i = 0; i < 8; ++i) {
      int off = i * 256 + lane * 4;
      f32x4 g4 = *(const f32x4*)(wg + off);
#pragma unroll
      for (int j = 0; j < TOPK; ++j) {
        f32x4 vv = *(const f32x4*)(&sh[j*D + off]);
        acc[j] += vv[0]*g4[0] + vv[1]*g4[1] + vv[2]*g4[2] + vv[3]*g4[3];
      }
    }
    for (int off = 32; off; off >>= 1)
#pragma unroll
      for (int j = 0; j < TOPK; ++j) acc[j] += __shfl_xor(acc[j], off, 64);
    if (lane == 0)
      for (int j = 0; j < TOPK; ++j) VW[j*D + c] = acc[j];
  } else if (bid == 576) {
    for (int j = 0; j < TOPK; ++j) {
      float s = 0.f;
      for (int t = tid; t < D; t += 256) s += bq[t] * kb[j*D + t];
      sh[tid] = s; __syncthreads();
      for (int w = 128; w > 0; w >>= 1) { if (tid < w) sh[tid] += sh[tid + w]; __syncthreads(); }
      if (tid == 0) sbias[j] = sh[0];
      __syncthreads();
    }
  } else {
    int base = (bid - 577) * 1024;
#pragma unroll
    for (int it = 0; it < 4; ++it) {
      int id = base + it * 256 + tid;
      int r = id >> 8;
      int cidx = id & 255;
      int kb_ = cidx >> 3, c = cidx & 7;
      const float* src = Wg + (size_t)r * (2 * D) + kb_ * 64 + c * 8;
      f32x4 a = *(const f32x4*)(src);
      f32x4 b = *(const f32x4*)(src + 4);
      s16x8 p;
      p[0]=(short)f2bf(a[0]); p[1]=(short)f2bf(a[1]); p[2]=(short)f2bf(a[2]); p[3]=(short)f2bf(a[3]);
      p[4]=(short)f2bf(b[0]); p[5]=(short)f2bf(b[1]); p[6]=(short)f2bf(b[2]); p[7]=(short)f2bf(b[3]);
      int dst = kb_ * 64 + ((c ^ (r & 7)) * 8);
      *(s16x8*)(B_sw + (size_t)r * D + dst) = p;
    }
  }
}

// ---------------- K5: scores + softmax -> attn[B][5]; fused no->bf16 swizzled cast ----------------
template <bool WRITE_CAST>
__global__ void k_attn(const float* __restrict__ no, const float* __restrict__ KQpart,
                       const float* __restrict__ sbias, const float* __restrict__ top_sims,
                       float* __restrict__ attn, unsigned short* __restrict__ A_sw) {
  __shared__ float kq[TOPK * D];
  int tid = threadIdx.x;
  for (int x = tid; x < TOPK * D; x += 256) {
    float s = 0.f;
#pragma unroll
    for (int cc = 0; cc < 8; ++cc) s += KQpart[(size_t)cc * TOPK * D + x];
    kq[x] = s;
  }
  __syncthreads();
  int lane = tid & 63, wid = tid >> 6;
  int gw = blockIdx.x * 4 + wid, nw = gridDim.x * 4;
  const float inv = 0.02209708691207961f;  // 1/sqrt(2048)
  for (int b = gw; b < B_ROWS; b += nw) {
    const float* row = no + (size_t)b * D;
    float acc[TOPK] = {0,0,0,0,0};
    int swz = (b & 7) << 4;
#pragma unroll 2
    for (int i = 0; i < 8; ++i) {
      int off = i * 256 + lane * 4;
      f32x4 n4 = *(const f32x4*)(row + off);
#pragma unroll
      for (int j = 0; j < TOPK; ++j) {
        f32x4 kv = *(const f32x4*)(&kq[j*D + off]);
        acc[j] += n4[0]*kv[0] + n4[1]*kv[1] + n4[2]*kv[2] + n4[3]*kv[3];
      }
      if (WRITE_CAST) {
        u16x4 c4;
        c4[0]=f2bf(n4[0]); c4[1]=f2bf(n4[1]); c4[2]=f2bf(n4[2]); c4[3]=f2bf(n4[3]);
        int bytecol = off * 2;
        *(u16x4*)((char*)A_sw + (size_t)b * (D*2) + (bytecol ^ swz)) = c4;
      }
    }
    for (int off = 32; off; off >>= 1)
#pragma unroll
      for (int j = 0; j < TOPK; ++j) acc[j] += __shfl_xor(acc[j], off, 64);
    if (lane == 0) {
      float s[TOPK], mx = -INFINITY;
      for (int j = 0; j < TOPK; ++j) { s[j] = (acc[j] + sbias[j]) * inv * top_sims[j]; mx = fmaxf(mx, s[j]); }
      float sum = 0.f;
      for (int j = 0; j < TOPK; ++j) { s[j] = __expf(s[j] - mx); sum += s[j]; }
      float r = 1.0f / sum;
      for (int j = 0; j < TOPK; ++j) attn[(size_t)b*TOPK + j] = s[j] * r;
    }
  }
}

// ---------------- K6 (fast): 2-phase double-buffered bf16 MFMA GEMM ----------------
// Swizzle discipline (rule #21): A_sw/B_sw are stored PRE-SWIZZLED in global
// (chunk c of row r lives at global chunk position c^(r&7)). Staging therefore
// uses LINEAR per-lane source addresses and a LINEAR LDS dest; the XOR is
// applied ONLY on the ds_read side. (Round-3 bug: an extra XOR on the source.)
union GemmSmem {
  struct { unsigned short A[2][128 * 64]; unsigned short B[2][128 * 64]; } s;  // 64 KB
  float ep[2048];  // epilogue alias (after K-loop)
};

__global__ __launch_bounds__(256) void k_gemm_bf(
    const unsigned short* __restrict__ A_sw, const unsigned short* __restrict__ B_sw,
    const float* __restrict__ no, const float* __restrict__ bg,
    const float* __restrict__ attn, const float* __restrict__ vb,
    const float* __restrict__ VW, float* __restrict__ out) {
  __shared__ GemmSmem sm;

  int tid = threadIdx.x;
  int lane = tid & 63, wid = tid >> 6;
  int fr = lane & 15, fg = lane >> 4;
  int wr = wid >> 1, wc = wid & 1;

  // XCD mapping: xcd = id&7 owns nt in {2*xcd, 2*xcd+1} (B-panel 1 MB, L2-resident);
  // mt-fast pairwise so consecutive blocks share the A-tile.
  int id = blockIdx.x;
  int xcd = id & 7, local_ = id >> 3;
  int nt = xcd * 2 + (local_ & 1);
  int mt = local_ >> 1;
  int brow = mt * 128, bcol = nt * 128;

  f32x4 acc[4][4];
#pragma unroll
  for (int m = 0; m < 4; ++m)
#pragma unroll
    for (int n = 0; n < 4; ++n) acc[m][n] = (f32x4){0.f, 0.f, 0.f, 0.f};

  // staging: chunk cid = i*256 + tid (0..1023), row = cid>>3, cc = cid&7 (LINEAR source)
  const unsigned short* gA[4];
  const unsigned short* gB[4];
  int lofs[4];
#pragma unroll
  for (int i = 0; i < 4; ++i) {
    int cid = i * 256 + tid;
    int row = cid >> 3, cc = cid & 7;
    gA[i] = A_sw + (size_t)(brow + row) * D + cc * 8;
    gB[i] = B_sw + (size_t)(bcol + row) * D + cc * 8;
    lofs[i] = (i * 256 + wid * 64) * 8;  // wave-uniform LDS element offset
  }

  // prologue: stage tile 0 into buf 0
#pragma unroll
  for (int i = 0; i < 4; ++i) {
    gload16(gA[i], sm.s.A[0] + lofs[i]);
    gload16(gB[i], sm.s.B[0] + lofs[i]);
  }
#pragma unroll
  for (int i = 0; i < 4; ++i) { gA[i] += 64; gB[i] += 64; }
  __syncthreads();

  int cur = 0;
  for (int kt = 0; kt < 32; ++kt) {
    if (kt < 31) {  // stage next tile into the other buffer (issued before compute)
#pragma unroll
      for (int i = 0; i < 4; ++i) {
        gload16(gA[i], sm.s.A[cur ^ 1] + lofs[i]);
        gload16(gB[i], sm.s.B[cur ^ 1] + lofs[i]);
      }
#pragma unroll
      for (int i = 0; i < 4; ++i) { gA[i] += 64; gB[i] += 64; }
    }
    const unsigned short* Ab = sm.s.A[cur];
    const unsigned short* Bb = sm.s.B[cur];
#pragma unroll
    for (int kk = 0; kk < 2; ++kk) {
      s16x8 af[4], bfr[4];
#pragma unroll
      for (int m = 0; m < 4; ++m) {
        int row = wr * 64 + m * 16 + fr;
        int addr = row * 128 + ((kk * 64 + fg * 16) ^ ((row & 7) << 4));
        af[m] = *(const s16x8*)((const char*)Ab + addr);
      }
#pragma unroll
      for (int n = 0; n < 4; ++n) {
        int row = wc * 64 + n * 16 + fr;
        int addr = row * 128 + ((kk * 64 + fg * 16) ^ ((row & 7) << 4));
        bfr[n] = *(const s16x8*)((const char*)Bb + addr);
      }
#pragma unroll
      for (int m = 0; m < 4; ++m)
#pragma unroll
        for (int n = 0; n < 4; ++n)
          acc[m][n] = __builtin_amdgcn_mfma_f32_16x16x32_bf16(af[m], bfr[n], acc[m][n], 0, 0, 0);
    }
    __syncthreads();  // drains vmcnt(0): next-tile loads landed; all reads of cur done
    cur ^= 1;
  }

  // epilogue staging (aliases the LDS buffers — safe after final barrier)
  for (int x = tid; x < 640; x += 256) sm.ep[x] = attn[(size_t)brow * TOPK + x];
  for (int x = tid; x < 640; x += 256) { int j = x >> 7, c = x & 127; sm.ep[640 + x]  = VW[j*D + bcol + c]; }
  for (int x = tid; x < 640; x += 256) { int j = x >> 7, c = x & 127; sm.ep[1280 + x] = vb[j*D + bcol + c]; }
  if (tid < 128) sm.ep[1920 + tid] = bg[bcol + tid];
  __syncthreads();

#pragma unroll
  for (int m = 0; m < 4; ++m) {
    int rbase = wr * 64 + m * 16 + fg * 4;
#pragma unroll
    for (int n = 0; n < 4; ++n) {
      int c = wc * 64 + n * 16 + fr;
      float vw0 = sm.ep[640 + 0*128 + c], vw1 = sm.ep[640 + 1*128 + c], vw2 = sm.ep[640 + 2*128 + c],
            vw3 = sm.ep[640 + 3*128 + c], vw4 = sm.ep[640 + 4*128 + c];
      float v0 = sm.ep[1280 + 0*128 + c], v1 = sm.ep[1280 + 1*128 + c], v2 = sm.ep[1280 + 2*128 + c],
            v3 = sm.ep[1280 + 3*128 + c], v4 = sm.ep[1280 + 4*128 + c];
      float bgc = sm.ep[1920 + c];
#pragma unroll
      for (int i = 0; i < 4; ++i) {
        int r = rbase + i;
        float a0 = sm.ep[r*5+0], a1 = sm.ep[r*5+1], a2 = sm.ep[r*5+2], a3 = sm.ep[r*5+3], a4 = sm.ep[r*5+4];
        float gl = acc[m][n][i] + bgc + a0*vw0 + a1*vw1 + a2*vw2 + a3*vw3 + a4*vw4;
        float att = a0*v0 + a1*v1 + a2*v2 + a3*v3 + a4*v4;
        float gate = 1.0f / (1.0f + __expf(-gl));
        size_t gi = (size_t)(brow + r) * D + bcol + c;
        out[gi] = no[gi] + gate * att;
      }
    }
  }
}

// ---------------- K6 (fallback): f32-staging GEMM ----------------
#define BM 128
#define BN 128
#define BKf 32
#define LDK (BKf + 8)

__global__ __launch_bounds__(256) void k_gemm_f32(
    const float* __restrict__ no, const float* __restrict__ Wg,
    const float* __restrict__ bg, const float* __restrict__ attn,
    const float* __restrict__ vb, const float* __restrict__ VW,
    float* __restrict__ out) {
  __shared__ unsigned short As[BM * LDK];
  __shared__ unsigned short Bs[BN * LDK];
  __shared__ float ep[2048];

  int tid = threadIdx.x;
  int lane = tid & 63, wid = tid >> 6;
  int brow = blockIdx.x * BM;
  int bcol = blockIdx.y * BN;
  int wr = wid >> 1, wc = wid & 1;

  f32x4 acc[4][4];
#pragma unroll
  for (int m = 0; m < 4; ++m)
#pragma unroll
    for (int n = 0; n < 4; ++n) acc[m][n] = (f32x4){0.f, 0.f, 0.f, 0.f};

  int fr = lane & 15, fg = lane >> 4;

  for (int kt = 0; kt < D / BKf; ++kt) {
    int k0 = kt * BKf;
#pragma unroll
    for (int i = 0; i < 4; ++i) {
      int fid = tid + i * 256;
      int row = fid >> 3, c4 = (fid & 7) * 4;
      f32x4 a4 = *(const f32x4*)(no + (size_t)(brow + row) * D + k0 + c4);
      f32x4 b4 = *(const f32x4*)(Wg + (size_t)(bcol + row) * (2 * D) + k0 + c4);
      u16x4 ab, bb;
      ab[0] = f2bf(a4[0]); ab[1] = f2bf(a4[1]); ab[2] = f2bf(a4[2]); ab[3] = f2bf(a4[3]);
      bb[0] = f2bf(b4[0]); bb[1] = f2bf(b4[1]); bb[2] = f2bf(b4[2]); bb[3] = f2bf(b4[3]);
      *(u16x4*)(&As[row * LDK + c4]) = ab;
      *(u16x4*)(&Bs[row * LDK + c4]) = bb;
    }
    __syncthreads();
    s16x8 af[4], bfr[4];
#pragma unroll
    for (int m = 0; m < 4; ++m) af[m] = *(const s16x8*)(&As[(wr*64 + m*16 + fr) * LDK + fg*8]);
#pragma unroll
    for (int n = 0; n < 4; ++n) bfr[n] = *(const s16x8*)(&Bs[(wc*64 + n*16 + fr) * LDK + fg*8]);
#pragma unroll
    for (int m = 0; m < 4; ++m)
#pragma unroll
      for (int n = 0; n < 4; ++n)
        acc[m][n] = __builtin_amdgcn_mfma_f32_16x16x32_bf16(af[m], bfr[n], acc[m][n], 0, 0, 0);
    __syncthreads();
  }

  for (int x = tid; x < 640; x += 256) ep[x] = attn[(size_t)brow * TOPK + x];
  for (int x = tid; x < 640; x += 256) { int j = x >> 7, c = x & 127; ep[640 + x]  = VW[j*D + bcol + c]; }
  for (int x = tid; x < 640; x += 256) { int j = x >> 7, c = x & 127; ep[1280 + x] = vb[j*D + bcol + c]; }
  if (tid < 128) ep[1920 + tid] = bg[bcol + tid];
  __syncthreads();

#pragma unroll
  for (int m = 0; m < 4; ++m) {
    int rbase = wr * 64 + m * 16 + fg * 4;
#pragma unroll
    for (int n = 0; n < 4; ++n) {
      int c = wc * 64 + n * 16 + fr;
      float vw0 = ep[640 + 0*128 + c], vw1 = ep[640 + 1*128 + c], vw2 = ep[640 + 2*128 + c],
            vw3 = ep[640 + 3*128 + c], vw4 = ep[640 + 4*128 + c];
      float v0 = ep[1280 + 0*128 + c], v1 = ep[1280 + 1*128 + c], v2 = ep[1280 + 2*128 + c],
            v3 = ep[1280 + 3*128 + c], v4 = ep[1280 + 4*128 + c];
      float bgc = ep[1920 + c];
#pragma unroll
      for (int i = 0; i < 4; ++i) {
        int r = rbase + i;
        float a0 = ep[r*5+0], a1 = ep[r*5+1], a2 = ep[r*5+2], a3 = ep[r*5+3], a4 = ep[r*5+4];
        float gl = acc[m][n][i] + bgc + a0*vw0 + a1*vw1 + a2*vw2 + a3*vw3 + a4*vw4;
        float att = a0*v0 + a1*v1 + a2*v2 + a3*v3 + a4*v4;
        float gate = 1.0f / (1.0f + __expf(-gl));
        size_t gi = (size_t)(brow + r) * D + bcol + c;
        out[gi] = no[gi] + gate * att;
      }
    }
  }
}

extern "C" void kernel_launch(void* const* d_in, const int* in_sizes, int n_in,
                              void* d_out, int out_size, void* d_ws, size_t ws_size,
                              hipStream_t stream) {
  (void)in_sizes; (void)n_in; (void)out_size;
  const float* no    = (const float*)d_in[0];
  const float* ce    = (const float*)d_in[1];
  const float* bank  = (const float*)d_in[2];
  const float* mvals = (const float*)d_in[3];
  const float* Wq    = (const float*)d_in[4];
  const float* bq    = (const float*)d_in[5];
  const float* Wk    = (const float*)d_in[6];
  const float* bk    = (const float*)d_in[7];
  const float* Wv    = (const float*)d_in[8];
  const float* bvp   = (const float*)d_in[9];
  const float* Wg    = (const float*)d_in[10];
  const float* bg    = (const float*)d_in[11];
  float* out = (float*)d_out;

  char* ws = (char*)d_ws;
  float* qn       = (float*)(ws + 0);
  float* sims     = (float*)(ws + 16384);
  float* top_sims = (float*)(ws + 220160);
  int*   top_idx  = (int*)  (ws + 220192);
  float* sbias    = (float*)(ws + 220224);
  float* kb       = (float*)(ws + 221184);
  float* vb       = (float*)(ws + 262144);
  float* VW       = (float*)(ws + 303104);
  float* KQpart   = (float*)(ws + 344064);
  float* attn     = (float*)(ws + 671744);
  unsigned short* A_sw = (unsigned short*)(ws + 1048576);
  unsigned short* B_sw = (unsigned short*)(ws + 1048576 + (size_t)B_ROWS * D * 2);

  const size_t ws_need = 1048576 + (size_t)B_ROWS * D * 2 + (size_t)D * D * 2;
  const bool fast = ws_size >= ws_need;

  k_qnorm<<<1, 256, 0, stream>>>(ce, qn);
  k_sims<<<1024, 256, 0, stream>>>(bank, qn, sims);
  k_topk<<<1, 256, 0, stream>>>(sims, top_sims, top_idx);
  k_kv<<<512, 256, 0, stream>>>(mvals, top_idx, Wk, bk, Wv, bvp, kb, vb);
  k_prep<<<fast ? 1089 : 577, 256, 0, stream>>>(Wq, bq, Wg, kb, vb, KQpart, VW, sbias, B_sw);
  if (fast) {
    k_attn<true><<<1024, 256, 0, stream>>>(no, KQpart, sbias, top_sims, attn, A_sw);
    k_gemm_bf<<<2048, 256, 0, stream>>>(A_sw, B_sw, no, bg, attn, vb, VW, out);
  } else {
    k_attn<false><<<1024, 256, 0, stream>>>(no, KQpart, sbias, top_sims, attn, A_sw);
    k_gemm_f32<<<dim3(B_ROWS / BM, D / BN), 256, 0, stream>>>(no, Wg, bg, attn, vb, VW, out);
  }
}

// Round 5
// 562.036 us; speedup vs baseline: 2.3086x; 1.1765x over previous
//
#include <hip/hip_runtime.h>
#include <hip/hip_bf16.h>
#include <math.h>

#define D 2048
#define M_ROWS 50000
#define B_ROWS 16384
#define TOPK 5
#define EPSN 1e-12f

typedef __attribute__((ext_vector_type(4))) float f32x4;
typedef __attribute__((ext_vector_type(8))) short s16x8;
typedef __attribute__((ext_vector_type(4))) unsigned short u16x4;

__device__ __forceinline__ unsigned short f2bf(float f) {
  union { float f; unsigned int u; } x; x.f = f;
  unsigned int u = x.u;
  unsigned int r = u + 0x7fffu + ((u >> 16) & 1u);
  return (unsigned short)(r >> 16);
}

__device__ __forceinline__ void gload16(const void* g, void* l) {
  __builtin_amdgcn_global_load_lds(
      (const __attribute__((address_space(1))) unsigned int*)g,
      (__attribute__((address_space(3))) unsigned int*)l, 16, 0, 0);
}

// ---------------- K0: q_norm ----------------
__global__ void k_qnorm(const float* __restrict__ ce, float* __restrict__ qn) {
  __shared__ float red[256];
  int tid = threadIdx.x;
  float s = 0.f;
  for (int t = tid; t < D; t += 256) { float x = ce[t]; s += x * x; }
  red[tid] = s; __syncthreads();
  for (int w = 128; w > 0; w >>= 1) { if (tid < w) red[tid] += red[tid + w]; __syncthreads(); }
  float inv = 1.0f / fmaxf(sqrtf(red[0]), EPSN);
  for (int t = tid; t < D; t += 256) qn[t] = ce[t] * inv;
}

// ---------------- K1: sims over memory bank ----------------
__global__ void k_sims(const float* __restrict__ bank, const float* __restrict__ qn,
                       float* __restrict__ sims) {
  __shared__ float qs[D];
  int tid = threadIdx.x;
  for (int t = tid; t < D; t += 256) qs[t] = qn[t];
  __syncthreads();
  int lane = tid & 63, wid = tid >> 6;
  int gw = (blockIdx.x << 2) + wid;
  int nw = gridDim.x << 2;
  for (int m = gw; m < M_ROWS; m += nw) {
    const float* row = bank + (size_t)m * D;
    float dot = 0.f, sq = 0.f;
#pragma unroll
    for (int i = 0; i < 8; ++i) {
      int off = i * 256 + lane * 4;
      f32x4 a = *(const f32x4*)(row + off);
      f32x4 q = *(const f32x4*)(qs + off);
      dot += a[0]*q[0] + a[1]*q[1] + a[2]*q[2] + a[3]*q[3];
      sq  += a[0]*a[0] + a[1]*a[1] + a[2]*a[2] + a[3]*a[3];
    }
    for (int off = 32; off; off >>= 1) {
      dot += __shfl_xor(dot, off, 64);
      sq  += __shfl_xor(sq,  off, 64);
    }
    if (lane == 0) sims[m] = dot / fmaxf(sqrtf(sq), EPSN);
  }
}

// ---------------- K2: top-5 ----------------
__global__ void k_topk(const float* __restrict__ sims, float* __restrict__ top_sims,
                       int* __restrict__ top_idx) {
  __shared__ float sval[256 * TOPK];
  __shared__ int   sidx[256 * TOPK];
  __shared__ float sv2[64 * TOPK];
  __shared__ int   si2[64 * TOPK];
  int tid = threadIdx.x;
  float lv[TOPK]; int li[TOPK];
#pragma unroll
  for (int j = 0; j < TOPK; ++j) { lv[j] = -INFINITY; li[j] = 0x7fffffff; }
  for (int m = tid; m < M_ROWS; m += 256) {
    float v = sims[m];
    if (v > lv[TOPK-1] || (v == lv[TOPK-1] && m < li[TOPK-1])) {
      lv[TOPK-1] = v; li[TOPK-1] = m;
#pragma unroll
      for (int j = TOPK-1; j > 0; --j) {
        bool sw = (lv[j] > lv[j-1]) || (lv[j] == lv[j-1] && li[j] < li[j-1]);
        if (sw) { float tv=lv[j]; lv[j]=lv[j-1]; lv[j-1]=tv; int ti=li[j]; li[j]=li[j-1]; li[j-1]=ti; }
      }
    }
  }
#pragma unroll
  for (int j = 0; j < TOPK; ++j) { sval[tid*TOPK+j] = lv[j]; sidx[tid*TOPK+j] = li[j]; }
  __syncthreads();
  if (tid < 64) {
    float bv[TOPK]; int bi[TOPK];
    for (int j = 0; j < TOPK; ++j) { bv[j] = -INFINITY; bi[j] = 0x7fffffff; }
    for (int c = tid * 20; c < tid * 20 + 20; ++c) {
      float v = sval[c]; int i = sidx[c];
      if (v > bv[TOPK-1] || (v == bv[TOPK-1] && i < bi[TOPK-1])) {
        bv[TOPK-1] = v; bi[TOPK-1] = i;
        for (int j = TOPK-1; j > 0; --j) {
          bool sw = (bv[j] > bv[j-1]) || (bv[j] == bv[j-1] && bi[j] < bi[j-1]);
          if (sw) { float tv=bv[j]; bv[j]=bv[j-1]; bv[j-1]=tv; int ti=bi[j]; bi[j]=bi[j-1]; bi[j-1]=ti; }
        }
      }
    }
    for (int j = 0; j < TOPK; ++j) { sv2[tid*TOPK+j] = bv[j]; si2[tid*TOPK+j] = bi[j]; }
  }
  __syncthreads();
  if (tid == 0) {
    float bvv[TOPK]; int bii[TOPK];
    for (int j = 0; j < TOPK; ++j) { bvv[j] = -INFINITY; bii[j] = 0x7fffffff; }
    for (int c = 0; c < 64 * TOPK; ++c) {
      float v = sv2[c]; int i = si2[c];
      if (v > bvv[TOPK-1] || (v == bvv[TOPK-1] && i < bii[TOPK-1])) {
        bvv[TOPK-1] = v; bii[TOPK-1] = i;
        for (int j = TOPK-1; j > 0; --j) {
          bool sw = (bvv[j] > bvv[j-1]) || (bvv[j] == bvv[j-1] && bii[j] < bii[j-1]);
          if (sw) { float tv=bvv[j]; bvv[j]=bvv[j-1]; bvv[j-1]=tv; int ti=bii[j]; bii[j]=bii[j-1]; bii[j-1]=ti; }
        }
      }
    }
    for (int j = 0; j < TOPK; ++j) { top_sims[j] = bvv[j]; top_idx[j] = bii[j]; }
  }
}

// ---------------- K3: k,v = memories @ Wk/Wv^T + b ----------------
__global__ void k_kv(const float* __restrict__ mvals, const int* __restrict__ top_idx,
                     const float* __restrict__ Wk, const float* __restrict__ bk,
                     const float* __restrict__ Wv, const float* __restrict__ bvp,
                     float* __restrict__ kb, float* __restrict__ vb) {
  __shared__ float mem[TOPK][D];
  int tid = threadIdx.x;
  for (int j = 0; j < TOPK; ++j) {
    const float* src = mvals + (size_t)top_idx[j] * D;
    for (int t = tid; t < D; t += 256) mem[j][t] = src[t];
  }
  __syncthreads();
  int lane = tid & 63, wid = tid >> 6;
  int c = blockIdx.x * 4 + wid;
  const float* wkr = Wk + (size_t)c * D;
  const float* wvr = Wv + (size_t)c * D;
  float ak[TOPK] = {0,0,0,0,0}, av[TOPK] = {0,0,0,0,0};
#pragma unroll 2
  for (int i = 0; i < 8; ++i) {
    int off = i * 256 + lane * 4;
    f32x4 wk4 = *(const f32x4*)(wkr + off);
    f32x4 wv4 = *(const f32x4*)(wvr + off);
#pragma unroll
    for (int j = 0; j < TOPK; ++j) {
      f32x4 mv = *(const f32x4*)(&mem[j][off]);
      ak[j] += mv[0]*wk4[0] + mv[1]*wk4[1] + mv[2]*wk4[2] + mv[3]*wk4[3];
      av[j] += mv[0]*wv4[0] + mv[1]*wv4[1] + mv[2]*wv4[2] + mv[3]*wv4[3];
    }
  }
  for (int off = 32; off; off >>= 1) {
#pragma unroll
    for (int j = 0; j < TOPK; ++j) {
      ak[j] += __shfl_xor(ak[j], off, 64);
      av[j] += __shfl_xor(av[j], off, 64);
    }
  }
  if (lane == 0) {
#pragma unroll
    for (int j = 0; j < TOPK; ++j) { kb[j*D + c] = ak[j] + bk[c]; vb[j*D + c] = av[j] + bvp[c]; }
  }
}

// ---------------- K4: prep — KQ partials (256 blk), VW, sbias, WgA bf16 cast ----------------
// grid: [0,256) KQ partials, [256,768) VW, 768 sbias, [769,1281) castB (fast path only)
__global__ void k_prep(const float* __restrict__ Wq, const float* __restrict__ bq,
                       const float* __restrict__ Wg,
                       const float* __restrict__ kb, const float* __restrict__ vb,
                       float* __restrict__ KQpart, float* __restrict__ VW,
                       float* __restrict__ sbias, unsigned short* __restrict__ B_sw) {
  __shared__ float sh[TOPK * D];
  int tid = threadIdx.x;
  int bid = blockIdx.x;
  if (bid < 256) {
    // KQpart[cc][j][t0..t0+255] over c-chunk cc of 64 rows
    int cc = bid >> 3, tc = bid & 7;
    for (int x = tid; x < TOPK * 64; x += 256) sh[x] = kb[(x >> 6) * D + cc * 64 + (x & 63)];
    __syncthreads();
    float acc[TOPK] = {0,0,0,0,0};
    const float* wq = Wq + (size_t)(cc * 64) * D + tc * 256 + tid;
#pragma unroll 4
    for (int c = 0; c < 64; ++c) {
      float w = wq[(size_t)c * D];
#pragma unroll
      for (int j = 0; j < TOPK; ++j) acc[j] += sh[j * 64 + c] * w;
    }
#pragma unroll
    for (int j = 0; j < TOPK; ++j)
      KQpart[(size_t)(cc * TOPK + j) * D + tc * 256 + tid] = acc[j];
  } else if (bid < 768) {
    for (int x = tid; x < TOPK * D; x += 256) sh[x] = vb[x];
    __syncthreads();
    int lane = tid & 63, wid = tid >> 6;
    int c = (bid - 256) * 4 + wid;
    const float* wg = Wg + (size_t)c * (2 * D) + D;
    float acc[TOPK] = {0,0,0,0,0};
#pragma unroll 2
    for (int i = 0; i < 8; ++i) {
      int off = i * 256 + lane * 4;
      f32x4 g4 = *(const f32x4*)(wg + off);
#pragma unroll
      for (int j = 0; j < TOPK; ++j) {
        f32x4 vv = *(const f32x4*)(&sh[j*D + off]);
        acc[j] += vv[0]*g4[0] + vv[1]*g4[1] + vv[2]*g4[2] + vv[3]*g4[3];
      }
    }
    for (int off = 32; off; off >>= 1)
#pragma unroll
      for (int j = 0; j < TOPK; ++j) acc[j] += __shfl_xor(acc[j], off, 64);
    if (lane == 0)
      for (int j = 0; j < TOPK; ++j) VW[j*D + c] = acc[j];
  } else if (bid == 768) {
    for (int j = 0; j < TOPK; ++j) {
      float s = 0.f;
      for (int t = tid; t < D; t += 256) s += bq[t] * kb[j*D + t];
      sh[tid] = s; __syncthreads();
      for (int w = 128; w > 0; w >>= 1) { if (tid < w) sh[tid] += sh[tid + w]; __syncthreads(); }
      if (tid == 0) sbias[j] = sh[0];
      __syncthreads();
    }
  } else {
    int base = (bid - 769) * 1024;
#pragma unroll
    for (int it = 0; it < 4; ++it) {
      int id = base + it * 256 + tid;
      int r = id >> 8;
      int cidx = id & 255;
      int kb_ = cidx >> 3, c = cidx & 7;
      const float* src = Wg + (size_t)r * (2 * D) + kb_ * 64 + c * 8;
      f32x4 a = *(const f32x4*)(src);
      f32x4 b = *(const f32x4*)(src + 4);
      s16x8 p;
      p[0]=(short)f2bf(a[0]); p[1]=(short)f2bf(a[1]); p[2]=(short)f2bf(a[2]); p[3]=(short)f2bf(a[3]);
      p[4]=(short)f2bf(b[0]); p[5]=(short)f2bf(b[1]); p[6]=(short)f2bf(b[2]); p[7]=(short)f2bf(b[3]);
      int dst = kb_ * 64 + ((c ^ (r & 7)) * 8);
      *(s16x8*)(B_sw + (size_t)r * D + dst) = p;
    }
  }
}

// ---------------- K4b: reduce 32 KQ partials -> KQ ----------------
__global__ void k_red(const float* __restrict__ KQpart, float* __restrict__ KQ) {
  int x = blockIdx.x * 256 + threadIdx.x;  // 40 blocks -> 10240
  float s = 0.f;
#pragma unroll 8
  for (int cc = 0; cc < 32; ++cc) s += KQpart[(size_t)cc * (TOPK * D) + x];
  KQ[x] = s;
}

// ---------------- K5: scores + softmax -> attn[B][5]; fused no->bf16 swizzled cast ----------------
template <bool WRITE_CAST>
__global__ void k_attn(const float* __restrict__ no, const float* __restrict__ KQ,
                       const float* __restrict__ sbias, const float* __restrict__ top_sims,
                       float* __restrict__ attn, unsigned short* __restrict__ A_sw) {
  __shared__ float kq[TOPK * D];
  int tid = threadIdx.x;
  for (int x = tid; x < TOPK * D; x += 256) kq[x] = KQ[x];
  __syncthreads();
  int lane = tid & 63, wid = tid >> 6;
  int gw = blockIdx.x * 4 + wid, nw = gridDim.x * 4;
  const float inv = 0.02209708691207961f;  // 1/sqrt(2048)
  for (int b = gw; b < B_ROWS; b += nw) {
    const float* row = no + (size_t)b * D;
    float acc[TOPK] = {0,0,0,0,0};
    int swz = (b & 7) << 4;
#pragma unroll 2
    for (int i = 0; i < 8; ++i) {
      int off = i * 256 + lane * 4;
      f32x4 n4 = *(const f32x4*)(row + off);
#pragma unroll
      for (int j = 0; j < TOPK; ++j) {
        f32x4 kv = *(const f32x4*)(&kq[j*D + off]);
        acc[j] += n4[0]*kv[0] + n4[1]*kv[1] + n4[2]*kv[2] + n4[3]*kv[3];
      }
      if (WRITE_CAST) {
        u16x4 c4;
        c4[0]=f2bf(n4[0]); c4[1]=f2bf(n4[1]); c4[2]=f2bf(n4[2]); c4[3]=f2bf(n4[3]);
        int bytecol = off * 2;
        *(u16x4*)((char*)A_sw + (size_t)b * (D*2) + (bytecol ^ swz)) = c4;
      }
    }
    for (int off = 32; off; off >>= 1)
#pragma unroll
      for (int j = 0; j < TOPK; ++j) acc[j] += __shfl_xor(acc[j], off, 64);
    if (lane == 0) {
      float s[TOPK], mx = -INFINITY;
      for (int j = 0; j < TOPK; ++j) { s[j] = (acc[j] + sbias[j]) * inv * top_sims[j]; mx = fmaxf(mx, s[j]); }
      float sum = 0.f;
      for (int j = 0; j < TOPK; ++j) { s[j] = __expf(s[j] - mx); sum += s[j]; }
      float r = 1.0f / sum;
      for (int j = 0; j < TOPK; ++j) attn[(size_t)b*TOPK + j] = s[j] * r;
    }
  }
}

// ---------------- K6 (fast): 256x256 2-phase double-buffered bf16 MFMA GEMM ----------------
// Swizzle discipline (rule #21): A_sw/B_sw stored PRE-SWIZZLED (chunk c of row r at
// position c^(r&7) within each 64-elem K-segment). Staging: LINEAR source + LINEAR
// LDS dest; XOR applied ONLY on ds_read. (Identical formulas to proven round-4 kernel.)
union GemmSmem {
  struct { unsigned short A[2][256 * 64]; unsigned short B[2][256 * 64]; } s;  // 128 KB
  float ep[4096];  // 16 KB epilogue alias (after final barrier)
};

__global__ __launch_bounds__(512, 2) void k_gemm_bf(
    const unsigned short* __restrict__ A_sw, const unsigned short* __restrict__ B_sw,
    const float* __restrict__ no, const float* __restrict__ bg,
    const float* __restrict__ attn, const float* __restrict__ vb,
    const float* __restrict__ VW, float* __restrict__ out) {
  __shared__ GemmSmem sm;

  int tid = threadIdx.x;
  int lane = tid & 63, wid = tid >> 6;     // 8 waves
  int fr = lane & 15, fg = lane >> 4;
  int wr = wid >> 2, wc = wid & 3;          // 2 (M) x 4 (N)

  // XCD map: xcd = id&7 owns column nt (B-panel 256x2048x2B = 1 MB, L2-resident);
  // consecutive ids (different XCDs) share the same mt row-panel via L3.
  int id = blockIdx.x;                      // 512 blocks
  int nt = id & 7, mt = id >> 3;            // nt 0..7, mt 0..63
  int brow = mt * 256, bcol = nt * 256;

  f32x4 acc[8][4];
#pragma unroll
  for (int m = 0; m < 8; ++m)
#pragma unroll
    for (int n = 0; n < 4; ++n) acc[m][n] = (f32x4){0.f, 0.f, 0.f, 0.f};

  // staging: chunk cid = i*512 + tid (0..2047), row = cid>>3, cc = cid&7 (LINEAR)
  const unsigned short* gA[4];
  const unsigned short* gB[4];
  int lofs[4];
#pragma unroll
  for (int i = 0; i < 4; ++i) {
    int cid = i * 512 + tid;
    int row = cid >> 3, cc = cid & 7;
    gA[i] = A_sw + (size_t)(brow + row) * D + cc * 8;
    gB[i] = B_sw + (size_t)(bcol + row) * D + cc * 8;
    lofs[i] = (i * 512 + wid * 64) * 8;  // wave-uniform LDS element offset
  }

  // prologue: stage tile 0 into buf 0
#pragma unroll
  for (int i = 0; i < 4; ++i) {
    gload16(gA[i], sm.s.A[0] + lofs[i]);
    gload16(gB[i], sm.s.B[0] + lofs[i]);
  }
#pragma unroll
  for (int i = 0; i < 4; ++i) { gA[i] += 64; gB[i] += 64; }
  __syncthreads();

  int cur = 0;
  for (int kt = 0; kt < 32; ++kt) {
    if (kt < 31) {
#pragma unroll
      for (int i = 0; i < 4; ++i) {
        gload16(gA[i], sm.s.A[cur ^ 1] + lofs[i]);
        gload16(gB[i], sm.s.B[cur ^ 1] + lofs[i]);
      }
#pragma unroll
      for (int i = 0; i < 4; ++i) { gA[i] += 64; gB[i] += 64; }
    }
    const unsigned short* Ab = sm.s.A[cur];
    const unsigned short* Bb = sm.s.B[cur];
#pragma unroll
    for (int kk = 0; kk < 2; ++kk) {
      s16x8 af[8], bfr[4];
#pragma unroll
      for (int m = 0; m < 8; ++m) {
        int row = wr * 128 + m * 16 + fr;
        int addr = row * 128 + ((kk * 64 + fg * 16) ^ ((row & 7) << 4));
        af[m] = *(const s16x8*)((const char*)Ab + addr);
      }
#pragma unroll
      for (int n = 0; n < 4; ++n) {
        int row = wc * 64 + n * 16 + fr;
        int addr = row * 128 + ((kk * 64 + fg * 16) ^ ((row & 7) << 4));
        bfr[n] = *(const s16x8*)((const char*)Bb + addr);
      }
#pragma unroll
      for (int m = 0; m < 8; ++m)
#pragma unroll
        for (int n = 0; n < 4; ++n)
          acc[m][n] = __builtin_amdgcn_mfma_f32_16x16x32_bf16(af[m], bfr[n], acc[m][n], 0, 0, 0);
    }
    __syncthreads();  // drains vmcnt(0): next-tile loads landed; all reads of cur done
    cur ^= 1;
  }

  // epilogue staging (aliases LDS; after final barrier)
  for (int x = tid; x < 1280; x += 512) sm.ep[x] = attn[(size_t)brow * TOPK + x];
  for (int x = tid; x < 1280; x += 512) { int j = x >> 8, c = x & 255; sm.ep[1280 + x] = VW[j*D + bcol + c]; }
  for (int x = tid; x < 1280; x += 512) { int j = x >> 8, c = x & 255; sm.ep[2560 + x] = vb[j*D + bcol + c]; }
  if (tid < 256) sm.ep[3840 + tid] = bg[bcol + tid];
  __syncthreads();

#pragma unroll
  for (int m = 0; m < 8; ++m) {
    int rbase = wr * 128 + m * 16 + fg * 4;
#pragma unroll
    for (int n = 0; n < 4; ++n) {
      int c = wc * 64 + n * 16 + fr;
      float vw0 = sm.ep[1280 + 0*256 + c], vw1 = sm.ep[1280 + 1*256 + c], vw2 = sm.ep[1280 + 2*256 + c],
            vw3 = sm.ep[1280 + 3*256 + c], vw4 = sm.ep[1280 + 4*256 + c];
      float v0 = sm.ep[2560 + 0*256 + c], v1 = sm.ep[2560 + 1*256 + c], v2 = sm.ep[2560 + 2*256 + c],
            v3 = sm.ep[2560 + 3*256 + c], v4 = sm.ep[2560 + 4*256 + c];
      float bgc = sm.ep[3840 + c];
#pragma unroll
      for (int i = 0; i < 4; ++i) {
        int r = rbase + i;
        float a0 = sm.ep[r*5+0], a1 = sm.ep[r*5+1], a2 = sm.ep[r*5+2], a3 = sm.ep[r*5+3], a4 = sm.ep[r*5+4];
        float gl = acc[m][n][i] + bgc + a0*vw0 + a1*vw1 + a2*vw2 + a3*vw3 + a4*vw4;
        float att = a0*v0 + a1*v1 + a2*v2 + a3*v3 + a4*v4;
        float gate = 1.0f / (1.0f + __expf(-gl));
        size_t gi = (size_t)(brow + r) * D + bcol + c;
        out[gi] = no[gi] + gate * att;
      }
    }
  }
}

// ---------------- K6 (fallback): f32-staging GEMM ----------------
#define BM 128
#define BN 128
#define BKf 32
#define LDK (BKf + 8)

__global__ __launch_bounds__(256) void k_gemm_f32(
    const float* __restrict__ no, const float* __restrict__ Wg,
    const float* __restrict__ bg, const float* __restrict__ attn,
    const float* __restrict__ vb, const float* __restrict__ VW,
    float* __restrict__ out) {
  __shared__ unsigned short As[BM * LDK];
  __shared__ unsigned short Bs[BN * LDK];
  __shared__ float ep[2048];

  int tid = threadIdx.x;
  int lane = tid & 63, wid = tid >> 6;
  int brow = blockIdx.x * BM;
  int bcol = blockIdx.y * BN;
  int wr = wid >> 1, wc = wid & 1;

  f32x4 acc[4][4];
#pragma unroll
  for (int m = 0; m < 4; ++m)
#pragma unroll
    for (int n = 0; n < 4; ++n) acc[m][n] = (f32x4){0.f, 0.f, 0.f, 0.f};

  int fr = lane & 15, fg = lane >> 4;

  for (int kt = 0; kt < D / BKf; ++kt) {
    int k0 = kt * BKf;
#pragma unroll
    for (int i = 0; i < 4; ++i) {
      int fid = tid + i * 256;
      int row = fid >> 3, c4 = (fid & 7) * 4;
      f32x4 a4 = *(const f32x4*)(no + (size_t)(brow + row) * D + k0 + c4);
      f32x4 b4 = *(const f32x4*)(Wg + (size_t)(bcol + row) * (2 * D) + k0 + c4);
      u16x4 ab, bb;
      ab[0] = f2bf(a4[0]); ab[1] = f2bf(a4[1]); ab[2] = f2bf(a4[2]); ab[3] = f2bf(a4[3]);
      bb[0] = f2bf(b4[0]); bb[1] = f2bf(b4[1]); bb[2] = f2bf(b4[2]); bb[3] = f2bf(b4[3]);
      *(u16x4*)(&As[row * LDK + c4]) = ab;
      *(u16x4*)(&Bs[row * LDK + c4]) = bb;
    }
    __syncthreads();
    s16x8 af[4], bfr[4];
#pragma unroll
    for (int m = 0; m < 4; ++m) af[m] = *(const s16x8*)(&As[(wr*64 + m*16 + fr) * LDK + fg*8]);
#pragma unroll
    for (int n = 0; n < 4; ++n) bfr[n] = *(const s16x8*)(&Bs[(wc*64 + n*16 + fr) * LDK + fg*8]);
#pragma unroll
    for (int m = 0; m < 4; ++m)
#pragma unroll
      for (int n = 0; n < 4; ++n)
        acc[m][n] = __builtin_amdgcn_mfma_f32_16x16x32_bf16(af[m], bfr[n], acc[m][n], 0, 0, 0);
    __syncthreads();
  }

  for (int x = tid; x < 640; x += 256) ep[x] = attn[(size_t)brow * TOPK + x];
  for (int x = tid; x < 640; x += 256) { int j = x >> 7, c = x & 127; ep[640 + x]  = VW[j*D + bcol + c]; }
  for (int x = tid; x < 640; x += 256) { int j = x >> 7, c = x & 127; ep[1280 + x] = vb[j*D + bcol + c]; }
  if (tid < 128) ep[1920 + tid] = bg[bcol + tid];
  __syncthreads();

#pragma unroll
  for (int m = 0; m < 4; ++m) {
    int rbase = wr * 64 + m * 16 + fg * 4;
#pragma unroll
    for (int n = 0; n < 4; ++n) {
      int c = wc * 64 + n * 16 + fr;
      float vw0 = ep[640 + 0*128 + c], vw1 = ep[640 + 1*128 + c], vw2 = ep[640 + 2*128 + c],
            vw3 = ep[640 + 3*128 + c], vw4 = ep[640 + 4*128 + c];
      float v0 = ep[1280 + 0*128 + c], v1 = ep[1280 + 1*128 + c], v2 = ep[1280 + 2*128 + c],
            v3 = ep[1280 + 3*128 + c], v4 = ep[1280 + 4*128 + c];
      float bgc = ep[1920 + c];
#pragma unroll
      for (int i = 0; i < 4; ++i) {
        int r = rbase + i;
        float a0 = ep[r*5+0], a1 = ep[r*5+1], a2 = ep[r*5+2], a3 = ep[r*5+3], a4 = ep[r*5+4];
        float gl = acc[m][n][i] + bgc + a0*vw0 + a1*vw1 + a2*vw2 + a3*vw3 + a4*vw4;
        float att = a0*v0 + a1*v1 + a2*v2 + a3*v3 + a4*v4;
        float gate = 1.0f / (1.0f + __expf(-gl));
        size_t gi = (size_t)(brow + r) * D + bcol + c;
        out[gi] = no[gi] + gate * att;
      }
    }
  }
}

extern "C" void kernel_launch(void* const* d_in, const int* in_sizes, int n_in,
                              void* d_out, int out_size, void* d_ws, size_t ws_size,
                              hipStream_t stream) {
  (void)in_sizes; (void)n_in; (void)out_size;
  const float* no    = (const float*)d_in[0];
  const float* ce    = (const float*)d_in[1];
  const float* bank  = (const float*)d_in[2];
  const float* mvals = (const float*)d_in[3];
  const float* Wq    = (const float*)d_in[4];
  const float* bq    = (const float*)d_in[5];
  const float* Wk    = (const float*)d_in[6];
  const float* bk    = (const float*)d_in[7];
  const float* Wv    = (const float*)d_in[8];
  const float* bvp   = (const float*)d_in[9];
  const float* Wg    = (const float*)d_in[10];
  const float* bg    = (const float*)d_in[11];
  float* out = (float*)d_out;

  char* ws = (char*)d_ws;
  float* qn       = (float*)(ws + 0);         // 8 KB
  float* sims     = (float*)(ws + 16384);     // 200 KB
  float* top_sims = (float*)(ws + 220160);
  int*   top_idx  = (int*)  (ws + 220192);
  float* sbias    = (float*)(ws + 220224);
  float* kb       = (float*)(ws + 221184);    // 40 KB
  float* vb       = (float*)(ws + 262144);    // 40 KB
  float* VW       = (float*)(ws + 303104);    // 40 KB
  float* KQpart   = (float*)(ws + 344064);    // 32*5*2048*4 = 1.31 MB -> ends 1654784
  float* KQ       = (float*)(ws + 1654784);   // 40 KB -> ends 1695744
  float* attn     = (float*)(ws + 1695744);   // 327 KB -> ends 2023424
  unsigned short* A_sw = (unsigned short*)(ws + 4194304);               // 64 MB
  unsigned short* B_sw = (unsigned short*)(ws + 4194304 + (size_t)B_ROWS * D * 2);  // 8 MB

  const size_t ws_need = 4194304 + (size_t)B_ROWS * D * 2 + (size_t)D * D * 2;
  const bool fast = ws_size >= ws_need;

  k_qnorm<<<1, 256, 0, stream>>>(ce, qn);
  k_sims<<<1024, 256, 0, stream>>>(bank, qn, sims);
  k_topk<<<1, 256, 0, stream>>>(sims, top_sims, top_idx);
  k_kv<<<512, 256, 0, stream>>>(mvals, top_idx, Wk, bk, Wv, bvp, kb, vb);
  k_prep<<<fast ? 1281 : 769, 256, 0, stream>>>(Wq, bq, Wg, kb, vb, KQpart, VW, sbias, B_sw);
  k_red<<<40, 256, 0, stream>>>(KQpart, KQ);
  if (fast) {
    k_attn<true><<<1024, 256, 0, stream>>>(no, KQ, sbias, top_sims, attn, A_sw);
    k_gemm_bf<<<512, 512, 0, stream>>>(A_sw, B_sw, no, bg, attn, vb, VW, out);
  } else {
    k_attn<false><<<1024, 256, 0, stream>>>(no, KQ, sbias, top_sims, attn, A_sw);
    k_gemm_f32<<<dim3(B_ROWS / BM, D / BN), 256, 0, stream>>>(no, Wg, bg, attn, vb, VW, out);
  }
}